// Round 1
// baseline (4234.037 us; speedup 1.0000x reference)
//
#include <hip/hip_runtime.h>
#include <hip/hip_bf16.h>
#include <cfloat>

#define EPS 1e-5f

constexpr int Bb = 16, Dd = 512, Tt = 1024, Kk = 8192;
constexpr int Nq = Bb * Tt;          // 16384 queries
constexpr int MT = 64;               // query tile
constexpr int NT = 64;               // cluster tile
constexpr int DT = 32;               // d stage
constexpr int KSPLIT = 2;
constexpr int KH = Kk / KSPLIT;      // 4096

// ---------------- kernel A: e2d[k] = sum_d (es[k][d]/clip(u[k]))^2 in fp64 ----
__global__ __launch_bounds__(256) void e2_kernel(const float* __restrict__ es,
                                                 const float* __restrict__ usage,
                                                 double* __restrict__ e2d) {
    int wave = threadIdx.x >> 6;
    int lane = threadIdx.x & 63;
    int k = blockIdx.x * 4 + wave;
    float uc = fmaxf(usage[k], EPS);
    const float* row = es + (size_t)k * Dd;
    double acc = 0.0;
#pragma unroll
    for (int j = 0; j < Dd / 64; ++j) {
        float e = row[lane + 64 * j] / uc;   // exact fp32 div, matches reference emb
        acc = fma((double)e, (double)e, acc);
    }
#pragma unroll
    for (int off = 32; off >= 1; off >>= 1)
        acc += __shfl_down(acc, off, 64);
    if (lane == 0) e2d[k] = acc;
}

// ---------------- kernel B: distances + per-row argmin over half of K --------
__global__ __launch_bounds__(256) void dist_kernel(const float* __restrict__ x,
                                                   const float* __restrict__ es,
                                                   const float* __restrict__ usage,
                                                   const double* __restrict__ e2d,
                                                   double* __restrict__ bvw,
                                                   int* __restrict__ biw) {
    __shared__ float Xs[DT][MT];        // [d][m]
    __shared__ float Es[DT][NT + 4];    // [d][n], pad 68 to dodge bank conflicts
    __shared__ double rv[16][MT];
    __shared__ int    ri[16][MT];

    const int tid = threadIdx.x;
    const int mt = blockIdx.x >> 1;
    const int ks = blockIdx.x & 1;
    const int m0 = mt * MT;
    const int b  = m0 >> 10;            // T = 1024
    const int t0 = m0 & (Tt - 1);
    const float* xb = x + (size_t)b * Dd * Tt + t0;

    const int tm = tid & 15;            // 16 query-groups of 4
    const int tn = tid >> 4;            // 16 cluster-groups of 4

    double bv[4];
    int    bi[4];
#pragma unroll
    for (int i = 0; i < 4; ++i) { bv[i] = DBL_MAX; bi[i] = 0x7fffffff; }

    for (int nt = 0; nt < KH / NT; ++nt) {
        const int n0 = ks * KH + nt * NT;
        double acc[4][4];
#pragma unroll
        for (int i = 0; i < 4; ++i)
#pragma unroll
            for (int j = 0; j < 4; ++j) acc[i][j] = 0.0;

        for (int dsg = 0; dsg < Dd / DT; ++dsg) {
            const int d0 = dsg * DT;
            __syncthreads();
            // stage X tile: 32 d x 64 m  (coalesced along t)
#pragma unroll
            for (int j = 0; j < 2; ++j) {
                int lin = tid * 2 + j;             // [0,512) float4 slots
                int d = lin >> 4;
                int mq = (lin & 15) * 4;
                float4 g = *(const float4*)(xb + (size_t)(d0 + d) * Tt + mq);
                *(float4*)&Xs[d][mq] = g;
            }
            // stage ES tile: 64 n x 32 d, scale by exact division, transpose into [d][n]
#pragma unroll
            for (int j = 0; j < 2; ++j) {
                int lin = tid * 2 + j;             // [0,512) float4 slots
                int r = lin >> 3;                  // n row (8 float4 per row)
                int dq = (lin & 7) * 4;
                int n = n0 + r;
                float uc = fmaxf(usage[n], EPS);
                float4 e = *(const float4*)(es + (size_t)n * Dd + d0 + dq);
                Es[dq + 0][r] = e.x / uc;
                Es[dq + 1][r] = e.y / uc;
                Es[dq + 2][r] = e.z / uc;
                Es[dq + 3][r] = e.w / uc;
            }
            __syncthreads();
#pragma unroll
            for (int dd = 0; dd < DT; ++dd) {
                float4 a4 = *(const float4*)&Xs[dd][tm * 4];
                float4 b4 = *(const float4*)&Es[dd][tn * 4];
                double ax[4] = {(double)a4.x, (double)a4.y, (double)a4.z, (double)a4.w};
                double bx[4] = {(double)b4.x, (double)b4.y, (double)b4.z, (double)b4.w};
#pragma unroll
                for (int i = 0; i < 4; ++i)
#pragma unroll
                    for (int j = 0; j < 4; ++j)
                        acc[i][j] = fma(ax[i], bx[j], acc[i][j]);
            }
        }
        // score this n-tile: d2 - x2 = e2[n] - 2*dot  (x2 constant per row)
#pragma unroll
        for (int j = 0; j < 4; ++j) {
            int n = n0 + tn * 4 + j;
            double e2 = e2d[n];
#pragma unroll
            for (int i = 0; i < 4; ++i) {
                double s = fma(-2.0, acc[i][j], e2);
                if (s < bv[i]) { bv[i] = s; bi[i] = n; }   // n strictly increasing -> first-min kept
            }
        }
    }

    // cross-thread (tn) reduction per query row
#pragma unroll
    for (int i = 0; i < 4; ++i) {
        rv[tn][tm * 4 + i] = bv[i];
        ri[tn][tm * 4 + i] = bi[i];
    }
    __syncthreads();
    if (tid < MT) {
        double v = rv[0][tid];
        int idx = ri[0][tid];
#pragma unroll
        for (int t = 1; t < 16; ++t) {
            double v2 = rv[t][tid];
            int i2 = ri[t][tid];
            if (v2 < v || (v2 == v && i2 < idx)) { v = v2; idx = i2; }
        }
        bvw[ks * Nq + m0 + tid] = v;
        biw[ks * Nq + m0 + tid] = idx;
    }
}

// ---------------- kernel C: merge halves, write codes (as float) + gather ----
__global__ __launch_bounds__(256) void gather_kernel(const float* __restrict__ es,
                                                     const float* __restrict__ usage,
                                                     const double* __restrict__ bvw,
                                                     const int* __restrict__ biw,
                                                     float* __restrict__ out) {
    __shared__ int   cs[64];
    __shared__ float us[64];
    const int tid = threadIdx.x;
    const int m0 = blockIdx.x * 64;
    const int b  = m0 >> 10;
    const int t0 = m0 & (Tt - 1);

    if (tid < 64) {
        int m = m0 + tid;
        double v0 = bvw[m], v1 = bvw[Nq + m];
        int i0 = biw[m], i1 = biw[Nq + m];
        int c = (v1 < v0) ? i1 : i0;       // tie -> lower half (smaller index)
        cs[tid] = c;
        us[tid] = fmaxf(usage[c], EPS);
        out[m] = (float)c;                 // codes stored as float
    }
    __syncthreads();
    const int tq = tid & 63;               // t within tile (wave-coalesced stores)
    const int dg = tid >> 6;               // 4 d-segments of 128
    const int c = cs[tq];
    const float uc = us[tq];
    const float* row = es + (size_t)c * Dd;
    float* ob = out + Nq + (size_t)b * Dd * Tt + t0 + tq;
    for (int d = dg * 128; d < dg * 128 + 128; ++d) {
        ob[(size_t)d * Tt] = row[d] / uc;  // exact fp32 div matches reference emb
    }
}

extern "C" void kernel_launch(void* const* d_in, const int* in_sizes, int n_in,
                              void* d_out, int out_size, void* d_ws, size_t ws_size,
                              hipStream_t stream) {
    const float* x     = (const float*)d_in[0];   // (16, 512, 1024)
    const float* es    = (const float*)d_in[1];   // (8192, 512)
    const float* usage = (const float*)d_in[2];   // (8192,)
    float* out = (float*)d_out;                   // [16384 codes][8388608 quantized]

    double* e2d = (double*)d_ws;                  // K doubles
    double* bvw = e2d + Kk;                       // 2*Nq doubles
    int*    biw = (int*)(bvw + 2 * Nq);           // 2*Nq ints  (total ~459 KB)

    e2_kernel<<<Kk / 4, 256, 0, stream>>>(es, usage, e2d);
    dist_kernel<<<(Nq / MT) * KSPLIT, 256, 0, stream>>>(x, es, usage, e2d, bvw, biw);
    gather_kernel<<<Nq / 64, 256, 0, stream>>>(es, usage, bvw, biw, out);
}

// Round 2
// 1735.195 us; speedup vs baseline: 2.4401x; 2.4401x over previous
//
#include <hip/hip_runtime.h>
#include <hip/hip_bf16.h>
#include <cfloat>
#include <stdint.h>

#define EPS 1e-5f
constexpr int Dd = 512, Tt = 1024, Kk = 8192;
constexpr int Nq = 16 * 1024;          // B*T queries
constexpr float TAU = 0.01f;           // flag margin for exact rescoring

typedef __bf16 bf16x8 __attribute__((ext_vector_type(8)));
typedef float  f32x4  __attribute__((ext_vector_type(4)));

union Pack8 { __bf16 h[8]; int4 v; };

__device__ __forceinline__ void gld16(const void* g, void* l) {
    __builtin_amdgcn_global_load_lds(
        (const __attribute__((address_space(1))) uint32_t*)g,
        (__attribute__((address_space(3))) uint32_t*)l, 16, 0, 0);
}

// ---------- init: zero flag counter (ws is re-poisoned every call) ----------
__global__ void init_kernel(int* cnt) {
    if (threadIdx.x == 0 && blockIdx.x == 0) *cnt = 0;
}

// ---------- P1: x (B,D,T) -> Xh,Xm (B*T, D) bf16 Dekker split --------------
__global__ __launch_bounds__(256) void split_x_kernel(const float* __restrict__ x,
                                                      ushort* __restrict__ Xh,
                                                      ushort* __restrict__ Xm) {
    __shared__ float Ls[64][68];                  // 64 d x 64 t tile, padded
    const int tid = threadIdx.x, bid = blockIdx.x;
    const int b  = bid >> 7;
    const int d0 = ((bid >> 4) & 7) * 64;
    const int t0 = (bid & 15) * 64;
    const float* xb = x + ((size_t)b * Dd + d0) * Tt + t0;
#pragma unroll
    for (int it = 0; it < 4; ++it) {
        int s = it * 256 + tid;
        int d = s >> 4, c = (s & 15) * 4;
        float4 g = *(const float4*)(xb + (size_t)d * Tt + c);
        *(float4*)&Ls[d][c] = g;
    }
    __syncthreads();
    const int t = tid >> 2;
    const int dseg = (tid & 3) * 16;
    Pack8 ph[2], pm[2];
#pragma unroll
    for (int dd = 0; dd < 16; ++dd) {
        float v = Ls[dseg + dd][t];
        __bf16 h = (__bf16)v;
        __bf16 m = (__bf16)(v - (float)h);        // exact residual (Dekker)
        ph[dd >> 3].h[dd & 7] = h;
        pm[dd >> 3].h[dd & 7] = m;
    }
    size_t base = ((size_t)(b * Tt + t0 + t)) * Dd + d0 + dseg;
    *(int4*)(Xh + base)     = ph[0].v;
    *(int4*)(Xh + base + 8) = ph[1].v;
    *(int4*)(Xm + base)     = pm[0].v;
    *(int4*)(Xm + base + 8) = pm[1].v;
}

// ---------- P2: emb = es/clip(u) -> Eh,Em bf16 split + embf fp32 + e2 -------
__global__ __launch_bounds__(256) void split_e_kernel(const float* __restrict__ es,
                                                      const float* __restrict__ usage,
                                                      ushort* __restrict__ Eh,
                                                      ushort* __restrict__ Em,
                                                      float* __restrict__ embf,
                                                      double* __restrict__ e2d,
                                                      float* __restrict__ e2f) {
    const int wave = threadIdx.x >> 6, lane = threadIdx.x & 63;
    const int k = blockIdx.x * 4 + wave;
    const float uc = fmaxf(usage[k], EPS);
    const float* row = es + (size_t)k * Dd;
    const int d = lane * 8;
    float4 a = *(const float4*)(row + d);
    float4 c = *(const float4*)(row + d + 4);
    float ef[8] = {a.x/uc, a.y/uc, a.z/uc, a.w/uc, c.x/uc, c.y/uc, c.z/uc, c.w/uc};
    Pack8 ph, pm;
    double e2 = 0.0;
#pragma unroll
    for (int j = 0; j < 8; ++j) {
        __bf16 h = (__bf16)ef[j];
        __bf16 m = (__bf16)(ef[j] - (float)h);
        ph.h[j] = h; pm.h[j] = m;
        e2 = fma((double)ef[j], (double)ef[j], e2);
    }
    size_t base = (size_t)k * Dd + d;
    *(int4*)(Eh + base) = ph.v;
    *(int4*)(Em + base) = pm.v;
    *(float4*)(embf + base)     = make_float4(ef[0], ef[1], ef[2], ef[3]);
    *(float4*)(embf + base + 4) = make_float4(ef[4], ef[5], ef[6], ef[7]);
#pragma unroll
    for (int off = 32; off >= 1; off >>= 1) e2 += __shfl_down(e2, off, 64);
    if (lane == 0) { e2d[k] = e2; e2f[k] = (float)e2; }
}

// ---------- main: 128x128 MFMA tile, 3-product split GEMM + top-2 epilogue --
__global__ __launch_bounds__(256) void gemm_kernel(const ushort* __restrict__ Xh,
                                                   const ushort* __restrict__ Xm,
                                                   const ushort* __restrict__ Eh,
                                                   const ushort* __restrict__ Em,
                                                   const float* __restrict__ e2f,
                                                   float4* __restrict__ colres) {
    __shared__ ushort Ahs[128 * 32], Ams[128 * 32], Bhs[128 * 32], Bms[128 * 32];
    __shared__ float rv1[2][128], rv2[2][128];
    __shared__ int   ri1[2][128];

    const int tid = threadIdx.x;
    const int nb = blockIdx.x & 63, mb = blockIdx.x >> 6;
    const int m0 = mb * 128, n0 = nb * 128;
    const int wave = tid >> 6, lane = tid & 63;
    const int mw = (wave >> 1) * 64, nw = (wave & 1) * 64;
    const int fm = lane & 15, fq = lane >> 4;

    f32x4 acc[4][4] = {};

    for (int d0 = 0; d0 < Dd; d0 += 32) {
#pragma unroll
        for (int j = 0; j < 2; ++j) {
            int s = j * 256 + tid;                 // lane-contiguous LDS dest
            int r = s >> 2;
            int c8 = (s & 3) * 8;
            size_t ga = (size_t)(m0 + r) * Dd + d0 + c8;
            size_t gb = (size_t)(n0 + r) * Dd + d0 + c8;
            gld16(Xh + ga, (char*)Ahs + s * 16);
            gld16(Xm + ga, (char*)Ams + s * 16);
            gld16(Eh + gb, (char*)Bhs + s * 16);
            gld16(Em + gb, (char*)Bms + s * 16);
        }
        __syncthreads();
        bf16x8 ah[4], am[4], bh[4], bm[4];
#pragma unroll
        for (int i = 0; i < 4; ++i) {
            int ra = (mw + i * 16 + fm) * 32 + fq * 8;
            int rb = (nw + i * 16 + fm) * 32 + fq * 8;
            ah[i] = *(const bf16x8*)&Ahs[ra];
            am[i] = *(const bf16x8*)&Ams[ra];
            bh[i] = *(const bf16x8*)&Bhs[rb];
            bm[i] = *(const bf16x8*)&Bms[rb];
        }
#pragma unroll
        for (int i = 0; i < 4; ++i)
#pragma unroll
            for (int j = 0; j < 4; ++j) {
                acc[i][j] = __builtin_amdgcn_mfma_f32_16x16x32_bf16(ah[i], bh[j], acc[i][j], 0, 0, 0);
                acc[i][j] = __builtin_amdgcn_mfma_f32_16x16x32_bf16(ah[i], bm[j], acc[i][j], 0, 0, 0);
                acc[i][j] = __builtin_amdgcn_mfma_f32_16x16x32_bf16(am[i], bh[j], acc[i][j], 0, 0, 0);
            }
        __syncthreads();
    }

    float e2r[4];
#pragma unroll
    for (int j = 0; j < 4; ++j) e2r[j] = e2f[n0 + nw + j * 16 + fm];

    // per-(row) top-2 over this block's 128 columns; C/D map: col=l&15, row=fq*4+r
#pragma unroll
    for (int i = 0; i < 4; ++i)
#pragma unroll
        for (int r = 0; r < 4; ++r) {
            float v1 = FLT_MAX, v2 = FLT_MAX; int i1 = 0x7fffffff;
#pragma unroll
            for (int j = 0; j < 4; ++j) {
                int n = n0 + nw + j * 16 + fm;
                float s = fmaf(-2.0f, acc[i][j][r], e2r[j]);   // x2 const dropped
                if (s < v1) { v2 = v1; v1 = s; i1 = n; }
                else if (s < v2) v2 = s;
            }
#pragma unroll
            for (int st = 1; st < 16; st <<= 1) {              // 16-lane butterfly
                float w1 = __shfl_xor(v1, st, 64);
                int   j1 = __shfl_xor(i1, st, 64);
                float w2 = __shfl_xor(v2, st, 64);
                if (w1 < v1 || (w1 == v1 && j1 < i1)) { v2 = fminf(v1, w2); v1 = w1; i1 = j1; }
                else v2 = fminf(v2, w1);
            }
            if (fm == 0) {
                int rl = mw + i * 16 + fq * 4 + r;
                rv1[wave & 1][rl] = v1;
                ri1[wave & 1][rl] = i1;
                rv2[wave & 1][rl] = v2;
            }
        }
    __syncthreads();
    if (tid < 128) {
        float a1 = rv1[0][tid], a2 = rv2[0][tid]; int ai = ri1[0][tid];
        float b1 = rv1[1][tid], b2 = rv2[1][tid]; int bi = ri1[1][tid];
        float v1, v2; int i1;
        if (b1 < a1 || (b1 == a1 && bi < ai)) { v1 = b1; i1 = bi; v2 = fminf(a1, b2); }
        else                                  { v1 = a1; i1 = ai; v2 = fminf(a2, b1); }
        colres[(size_t)(m0 + tid) * 64 + nb] = make_float4(v1, __int_as_float(i1), v2, 0.0f);
    }
}

// ---------- merge 64 col-blocks per row; flag near-ties ---------------------
__global__ __launch_bounds__(256) void merge_kernel(const float4* __restrict__ colres,
                                                    float* __restrict__ out,
                                                    int* __restrict__ cnt,
                                                    int* __restrict__ queue) {
    const int wave = threadIdx.x >> 6, lane = threadIdx.x & 63;
    const int row = blockIdx.x * 4 + wave;
    float4 e = colres[(size_t)row * 64 + lane];
    float v1 = e.x, v2 = e.z; int i1 = __float_as_int(e.y);
#pragma unroll
    for (int st = 1; st < 64; st <<= 1) {
        float w1 = __shfl_xor(v1, st, 64);
        int   j1 = __shfl_xor(i1, st, 64);
        float w2 = __shfl_xor(v2, st, 64);
        if (w1 < v1 || (w1 == v1 && j1 < i1)) { v2 = fminf(v1, w2); v1 = w1; i1 = j1; }
        else v2 = fminf(v2, w1);
    }
    if (lane == 0) {
        out[row] = (float)i1;
        if (v2 - v1 < TAU) {                    // near-tie: exact rescore later
            int p = atomicAdd(cnt, 1);
            queue[p] = row;
        }
    }
}

// ---------- exact fp64 rescore of flagged queries over all K ----------------
constexpr int QPB = 4;
__global__ __launch_bounds__(256) void fixup_kernel(const float* __restrict__ x,
                                                    const float* __restrict__ embf,
                                                    const double* __restrict__ e2d,
                                                    const int* __restrict__ cnt,
                                                    const int* __restrict__ queue,
                                                    float* __restrict__ out) {
    __shared__ float xs[QPB][512];
    __shared__ double rbv[256];
    __shared__ int rbi[256];
    __shared__ int qm[QPB];
    const int tid = threadIdx.x;
    const int n = *cnt;
    for (int base = blockIdx.x * QPB; base < n; base += gridDim.x * QPB) {
        const int nq = min(QPB, n - base);
        __syncthreads();
        for (int q = 0; q < nq; ++q) {
            int m = queue[base + q];
            if (tid == 0) qm[q] = m;
            int b = m >> 10, t = m & 1023;
            for (int d = tid; d < 512; d += 256)
                xs[q][d] = x[((size_t)b * 512 + d) * 1024 + t];
        }
        __syncthreads();
        double best[QPB]; int bidx[QPB];
#pragma unroll
        for (int q = 0; q < QPB; ++q) { best[q] = DBL_MAX; bidx[q] = 0x7fffffff; }
        for (int k = tid; k < Kk; k += 256) {
            const float* row = embf + (size_t)k * 512;
            double dot[QPB] = {0.0, 0.0, 0.0, 0.0};
            for (int d = 0; d < 512; d += 4) {
                float4 e = *(const float4*)(row + d);
#pragma unroll
                for (int q = 0; q < QPB; ++q) {
                    float4 xv = *(const float4*)&xs[q][d];
                    dot[q] = fma((double)e.x, (double)xv.x, dot[q]);
                    dot[q] = fma((double)e.y, (double)xv.y, dot[q]);
                    dot[q] = fma((double)e.z, (double)xv.z, dot[q]);
                    dot[q] = fma((double)e.w, (double)xv.w, dot[q]);
                }
            }
            double e2k = e2d[k];
#pragma unroll
            for (int q = 0; q < QPB; ++q) {
                double s = fma(-2.0, dot[q], e2k);
                if (s < best[q]) { best[q] = s; bidx[q] = k; }   // k increasing
            }
        }
        for (int q = 0; q < nq; ++q) {
            rbv[tid] = best[q]; rbi[tid] = bidx[q];
            __syncthreads();
            for (int off = 128; off > 0; off >>= 1) {
                if (tid < off) {
                    if (rbv[tid + off] < rbv[tid] ||
                        (rbv[tid + off] == rbv[tid] && rbi[tid + off] < rbi[tid])) {
                        rbv[tid] = rbv[tid + off]; rbi[tid] = rbi[tid + off];
                    }
                }
                __syncthreads();
            }
            if (tid == 0) out[qm[q]] = (float)rbi[0];
            __syncthreads();
        }
    }
}

// ---------- gather quantized rows (fp32-exact emb), coalesced along t -------
__global__ __launch_bounds__(256) void gather_kernel(const float* __restrict__ embf,
                                                     float* __restrict__ out) {
    __shared__ int cs[64];
    const int tid = threadIdx.x;
    const int m0 = blockIdx.x * 64;
    const int b = m0 >> 10;
    const int t0 = m0 & (Tt - 1);
    if (tid < 64) cs[tid] = (int)out[m0 + tid];
    __syncthreads();
    const int tq = tid & 63;
    const int dg = tid >> 6;
    const int c = cs[tq];
    const float* row = embf + (size_t)c * Dd;
    float* ob = out + Nq + (size_t)b * Dd * Tt + t0 + tq;
#pragma unroll 4
    for (int d = dg * 128; d < dg * 128 + 128; ++d)
        ob[(size_t)d * Tt] = row[d];
}

extern "C" void kernel_launch(void* const* d_in, const int* in_sizes, int n_in,
                              void* d_out, int out_size, void* d_ws, size_t ws_size,
                              hipStream_t stream) {
    const float* x     = (const float*)d_in[0];
    const float* es    = (const float*)d_in[1];
    const float* usage = (const float*)d_in[2];
    float* out = (float*)d_out;

    char* w = (char*)d_ws;
    ushort* Xh = (ushort*)w;   w += (size_t)Nq * Dd * 2;     // 16 MB
    ushort* Xm = (ushort*)w;   w += (size_t)Nq * Dd * 2;     // 16 MB
    ushort* Eh = (ushort*)w;   w += (size_t)Kk * Dd * 2;     //  8 MB
    ushort* Em = (ushort*)w;   w += (size_t)Kk * Dd * 2;     //  8 MB
    float*  embf = (float*)w;  w += (size_t)Kk * Dd * 4;     // 16 MB
    double* e2d = (double*)w;  w += (size_t)Kk * 8;
    float*  e2f = (float*)w;   w += (size_t)Kk * 4;
    float4* colres = (float4*)w; w += (size_t)Nq * 64 * 16;  // 16 MB
    int* cnt = (int*)w;        w += 256;
    int* queue = (int*)w;      w += (size_t)Nq * 4;

    init_kernel<<<1, 64, 0, stream>>>(cnt);
    split_x_kernel<<<2048, 256, 0, stream>>>(x, Xh, Xm);
    split_e_kernel<<<Kk / 4, 256, 0, stream>>>(es, usage, Eh, Em, embf, e2d, e2f);
    gemm_kernel<<<8192, 256, 0, stream>>>(Xh, Xm, Eh, Em, e2f, colres);
    merge_kernel<<<Nq / 4, 256, 0, stream>>>(colres, out, cnt, queue);
    fixup_kernel<<<64, 256, 0, stream>>>(x, embf, e2d, cnt, queue, out);
    gather_kernel<<<Nq / 64, 256, 0, stream>>>(embf, out);
}

// Round 3
// 664.715 us; speedup vs baseline: 6.3697x; 2.6104x over previous
//
#include <hip/hip_runtime.h>
#include <hip/hip_bf16.h>
#include <cfloat>
#include <stdint.h>

#define EPS 1e-5f
constexpr int Dd = 512, Tt = 1024, Kk = 8192;
constexpr int Nq = 16 * 1024;
constexpr float TAU = 0.05f;          // >=30x observed split-error scale

typedef __bf16 bf16x8 __attribute__((ext_vector_type(8)));
typedef float  f32x4  __attribute__((ext_vector_type(4)));
typedef unsigned long long u64;

union Pack8 { __bf16 h[8]; int4 v; };

__device__ __forceinline__ void gld16(const void* g, void* l) {
    __builtin_amdgcn_global_load_lds(
        (const __attribute__((address_space(1))) uint32_t*)g,
        (__attribute__((address_space(3))) uint32_t*)l, 16, 0, 0);
}

// monotone float->u32 key; pack with index (smaller value, then smaller index)
__device__ __forceinline__ u64 packSI(float s, int n) {
    unsigned u = __float_as_uint(s);
    u = (u & 0x80000000u) ? ~u : (u | 0x80000000u);
    return ((u64)u << 32) | (unsigned)n;
}
__device__ __forceinline__ float unpackS(u64 p) {
    unsigned u = (unsigned)(p >> 32);
    u = (u & 0x80000000u) ? (u ^ 0x80000000u) : ~u;
    return __uint_as_float(u);
}
__device__ __forceinline__ int unpackI(u64 p) { return (int)(unsigned)p; }

__device__ __forceinline__ u64 umin64(u64 a, u64 b) { return a < b ? a : b; }
__device__ __forceinline__ u64 umax64(u64 a, u64 b) { return a > b ? a : b; }

// merge two sorted triples -> smallest 3 of union
__device__ __forceinline__ void merge3(u64& a1, u64& a2, u64& a3, u64 b1, u64 b2, u64 b3) {
    u64 c1 = umin64(a1, b1);
    u64 t  = umax64(a1, b1);
    u64 u  = umin64(a2, b2);
    u64 c2 = umin64(t, u);
    u64 c3 = umin64(umax64(t, u), umin64(a3, b3));
    a1 = c1; a2 = c2; a3 = c3;
}

__device__ __forceinline__ u64 shflx64(u64 v, int m) {
    int lo = __shfl_xor((int)(unsigned)v, m, 64);
    int hi = __shfl_xor((int)(v >> 32), m, 64);
    return ((u64)(unsigned)hi << 32) | (unsigned)lo;
}

// ---------------- init: zero queue counters --------------------------------
__global__ void init_kernel(int* cnt) {
    if (threadIdx.x == 0 && blockIdx.x == 0) { cnt[0] = 0; cnt[1] = 0; }
}

// ---------------- P1: x (B,D,T) -> Xh,Xm bf16 Dekker split ------------------
__global__ __launch_bounds__(256) void split_x_kernel(const float* __restrict__ x,
                                                      ushort* __restrict__ Xh,
                                                      ushort* __restrict__ Xm) {
    __shared__ float Ls[64][68];
    const int tid = threadIdx.x, bid = blockIdx.x;
    const int b  = bid >> 7;
    const int d0 = ((bid >> 4) & 7) * 64;
    const int t0 = (bid & 15) * 64;
    const float* xb = x + ((size_t)b * Dd + d0) * Tt + t0;
#pragma unroll
    for (int it = 0; it < 4; ++it) {
        int s = it * 256 + tid;
        int d = s >> 4, c = (s & 15) * 4;
        float4 g = *(const float4*)(xb + (size_t)d * Tt + c);
        *(float4*)&Ls[d][c] = g;
    }
    __syncthreads();
    const int t = tid >> 2;
    const int dseg = (tid & 3) * 16;
    Pack8 ph[2], pm[2];
#pragma unroll
    for (int dd = 0; dd < 16; ++dd) {
        float v = Ls[dseg + dd][t];
        __bf16 h = (__bf16)v;
        __bf16 m = (__bf16)(v - (float)h);
        ph[dd >> 3].h[dd & 7] = h;
        pm[dd >> 3].h[dd & 7] = m;
    }
    size_t base = ((size_t)(b * Tt + t0 + t)) * Dd + d0 + dseg;
    *(int4*)(Xh + base)     = ph[0].v;
    *(int4*)(Xh + base + 8) = ph[1].v;
    *(int4*)(Xm + base)     = pm[0].v;
    *(int4*)(Xm + base + 8) = pm[1].v;
}

// ---------------- P2: emb=es/clip(u) -> Eh,Em bf16 split + e2 ---------------
__global__ __launch_bounds__(256) void split_e_kernel(const float* __restrict__ es,
                                                      const float* __restrict__ usage,
                                                      ushort* __restrict__ Eh,
                                                      ushort* __restrict__ Em,
                                                      double* __restrict__ e2d,
                                                      float* __restrict__ e2f) {
    const int wave = threadIdx.x >> 6, lane = threadIdx.x & 63;
    const int k = blockIdx.x * 4 + wave;
    const float uc = fmaxf(usage[k], EPS);
    const float* row = es + (size_t)k * Dd;
    const int d = lane * 8;
    float4 a = *(const float4*)(row + d);
    float4 c = *(const float4*)(row + d + 4);
    float ef[8] = {a.x/uc, a.y/uc, a.z/uc, a.w/uc, c.x/uc, c.y/uc, c.z/uc, c.w/uc};
    Pack8 ph, pm;
    double e2 = 0.0;
#pragma unroll
    for (int j = 0; j < 8; ++j) {
        __bf16 h = (__bf16)ef[j];
        __bf16 m = (__bf16)(ef[j] - (float)h);
        ph.h[j] = h; pm.h[j] = m;
        e2 = fma((double)ef[j], (double)ef[j], e2);
    }
    size_t base = (size_t)k * Dd + d;
    *(int4*)(Eh + base) = ph.v;
    *(int4*)(Em + base) = pm.v;
#pragma unroll
    for (int off = 32; off >= 1; off >>= 1) e2 += __shfl_down(e2, off, 64);
    if (lane == 0) { e2d[k] = e2; e2f[k] = (float)e2; }
}

// ---------------- main GEMM: 128x128 tile, 3-product split, top-3 epilogue --
__global__ __launch_bounds__(256) void gemm_kernel(const ushort* __restrict__ Xh,
                                                   const ushort* __restrict__ Xm,
                                                   const ushort* __restrict__ Eh,
                                                   const ushort* __restrict__ Em,
                                                   const float* __restrict__ e2f,
                                                   u64* __restrict__ colres) {
    __shared__ ushort Ahs[128 * 32], Ams[128 * 32], Bhs[128 * 32], Bms[128 * 32];
    __shared__ u64 trip[2][128][3];

    const int tid = threadIdx.x;
    const int nb = blockIdx.x & 63, mb = blockIdx.x >> 6;
    const int m0 = mb * 128, n0 = nb * 128;
    const int wave = tid >> 6, lane = tid & 63;
    const int mw = (wave >> 1) * 64, nw = (wave & 1) * 64;
    const int fm = lane & 15, fq = lane >> 4;

    f32x4 acc[4][4] = {};

    for (int d0 = 0; d0 < Dd; d0 += 32) {
#pragma unroll
        for (int j = 0; j < 2; ++j) {
            int s = j * 256 + tid;
            int r = s >> 2;
            int c8 = (s & 3) * 8;
            size_t ga = (size_t)(m0 + r) * Dd + d0 + c8;
            size_t gb = (size_t)(n0 + r) * Dd + d0 + c8;
            gld16(Xh + ga, (char*)Ahs + s * 16);
            gld16(Xm + ga, (char*)Ams + s * 16);
            gld16(Eh + gb, (char*)Bhs + s * 16);
            gld16(Em + gb, (char*)Bms + s * 16);
        }
        __syncthreads();
        bf16x8 ah[4], am[4], bh[4], bm[4];
#pragma unroll
        for (int i = 0; i < 4; ++i) {
            int ra = (mw + i * 16 + fm) * 32 + fq * 8;
            int rb = (nw + i * 16 + fm) * 32 + fq * 8;
            ah[i] = *(const bf16x8*)&Ahs[ra];
            am[i] = *(const bf16x8*)&Ams[ra];
            bh[i] = *(const bf16x8*)&Bhs[rb];
            bm[i] = *(const bf16x8*)&Bms[rb];
        }
#pragma unroll
        for (int i = 0; i < 4; ++i)
#pragma unroll
            for (int j = 0; j < 4; ++j) {
                acc[i][j] = __builtin_amdgcn_mfma_f32_16x16x32_bf16(ah[i], bh[j], acc[i][j], 0, 0, 0);
                acc[i][j] = __builtin_amdgcn_mfma_f32_16x16x32_bf16(ah[i], bm[j], acc[i][j], 0, 0, 0);
                acc[i][j] = __builtin_amdgcn_mfma_f32_16x16x32_bf16(am[i], bh[j], acc[i][j], 0, 0, 0);
            }
        __syncthreads();
    }

    float e2r[4];
#pragma unroll
    for (int j = 0; j < 4; ++j) e2r[j] = e2f[n0 + nw + j * 16 + fm];

    // top-3 per (row, 128-col block); C/D map: col=lane&15, row=fq*4+r
#pragma unroll
    for (int i = 0; i < 4; ++i)
#pragma unroll
        for (int r = 0; r < 4; ++r) {
            u64 q[4];
#pragma unroll
            for (int j = 0; j < 4; ++j) {
                float s = fmaf(-2.0f, acc[i][j][r], e2r[j]);
                q[j] = packSI(s, n0 + nw + j * 16 + fm);
            }
            u64 lo01 = umin64(q[0], q[1]), hi01 = umax64(q[0], q[1]);
            u64 lo23 = umin64(q[2], q[3]), hi23 = umax64(q[2], q[3]);
            u64 a1 = umin64(lo01, lo23);
            u64 m  = umax64(lo01, lo23), mm = umin64(hi01, hi23);
            u64 a2 = umin64(m, mm);
            u64 a3 = umin64(umax64(m, mm), umax64(hi01, hi23));
#pragma unroll
            for (int st = 1; st < 16; st <<= 1)
                merge3(a1, a2, a3, shflx64(a1, st), shflx64(a2, st), shflx64(a3, st));
            if (fm == 0) {
                int rl = mw + i * 16 + fq * 4 + r;
                trip[wave & 1][rl][0] = a1;
                trip[wave & 1][rl][1] = a2;
                trip[wave & 1][rl][2] = a3;
            }
        }
    __syncthreads();
    if (tid < 128) {
        u64 a1 = trip[0][tid][0], a2 = trip[0][tid][1], a3 = trip[0][tid][2];
        merge3(a1, a2, a3, trip[1][tid][0], trip[1][tid][1], trip[1][tid][2]);
        size_t o = ((size_t)(m0 + tid) * 64 + nb) * 3;
        colres[o] = a1; colres[o + 1] = a2; colres[o + 2] = a3;
    }
}

// ---------------- merge 64 col-blocks -> global top-3; tiered flagging ------
__global__ __launch_bounds__(256) void merge_kernel(const u64* __restrict__ colres,
                                                    float* __restrict__ out,
                                                    int* __restrict__ cnt,
                                                    int* __restrict__ queueP,
                                                    int* __restrict__ queueF) {
    const int wave = threadIdx.x >> 6, lane = threadIdx.x & 63;
    const int row = blockIdx.x * 4 + wave;
    size_t o = ((size_t)row * 64 + lane) * 3;
    u64 a1 = colres[o], a2 = colres[o + 1], a3 = colres[o + 2];
#pragma unroll
    for (int st = 1; st < 64; st <<= 1)
        merge3(a1, a2, a3, shflx64(a1, st), shflx64(a2, st), shflx64(a3, st));
    if (lane == 0) {
        float v1 = unpackS(a1), v2 = unpackS(a2), v3 = unpackS(a3);
        int i1 = unpackI(a1), i2 = unpackI(a2);
        out[row] = (float)i1;
        if (v3 - v1 < TAU) {                    // possible hidden 4th: exact full scan
            int p = atomicAdd(&cnt[1], 1);
            queueF[p] = row;
        } else if (v2 - v1 < TAU) {             // winner provably in {i1,i2}
            int p = atomicAdd(&cnt[0], 1);
            queueP[p * 3] = row; queueP[p * 3 + 1] = i1; queueP[p * 3 + 2] = i2;
        }
    }
}

// ---------------- pair rescore: exact fp64 on {i1,i2}, one wave per query ---
__global__ __launch_bounds__(256) void pair_kernel(const float* __restrict__ x,
                                                   const float* __restrict__ es,
                                                   const float* __restrict__ usage,
                                                   const double* __restrict__ e2d,
                                                   const int* __restrict__ cnt,
                                                   const int* __restrict__ queueP,
                                                   float* __restrict__ out) {
    const int wv = (blockIdx.x << 2) | (threadIdx.x >> 6);
    const int lane = threadIdx.x & 63;
    const int n = cnt[0];
    for (int p = wv; p < n; p += gridDim.x * 4) {
        int row = queueP[p * 3], i1 = queueP[p * 3 + 1], i2 = queueP[p * 3 + 2];
        int b = row >> 10, t = row & 1023;
        const float* xb = x + (size_t)b * Dd * Tt + t;
        float uc1 = fmaxf(usage[i1], EPS), uc2 = fmaxf(usage[i2], EPS);
        const float* e1 = es + (size_t)i1 * Dd + lane * 8;
        const float* e2 = es + (size_t)i2 * Dd + lane * 8;
        double s1 = 0.0, s2 = 0.0;
#pragma unroll
        for (int j = 0; j < 8; ++j) {
            double xv = (double)xb[(size_t)(lane * 8 + j) * Tt];
            s1 = fma(xv, (double)(e1[j] / uc1), s1);   // fp32 div == reference emb
            s2 = fma(xv, (double)(e2[j] / uc2), s2);
        }
#pragma unroll
        for (int off = 32; off >= 1; off >>= 1) {
            s1 += __shfl_down(s1, off, 64);
            s2 += __shfl_down(s2, off, 64);
        }
        if (lane == 0) {
            double d1 = fma(-2.0, s1, e2d[i1]);
            double d2 = fma(-2.0, s2, e2d[i2]);
            int c = (d2 < d1 || (d2 == d1 && i2 < i1)) ? i2 : i1;
            out[row] = (float)c;
        }
    }
}

// ---------------- rare full exact scan: 16 chunks x 512 clusters per query --
__global__ __launch_bounds__(256) void fscan_kernel(const float* __restrict__ x,
                                                    const float* __restrict__ es,
                                                    const float* __restrict__ usage,
                                                    const double* __restrict__ e2d,
                                                    const int* __restrict__ cnt,
                                                    const int* __restrict__ queueF,
                                                    double* __restrict__ fbv,
                                                    int* __restrict__ fbi) {
    __shared__ float xs[512];
    __shared__ double sv[256];
    __shared__ int si[256];
    const int tid = threadIdx.x;
    const int ntask = cnt[1] * 16;
    for (int task = blockIdx.x; task < ntask; task += gridDim.x) {
        int qi = task >> 4, ch = task & 15;
        int row = queueF[qi];
        int b = row >> 10, t = row & 1023;
        __syncthreads();
        for (int d = tid; d < Dd; d += 256)
            xs[d] = x[((size_t)b * Dd + d) * Tt + t];
        __syncthreads();
        double bv = DBL_MAX; int bi = 0x7fffffff;
#pragma unroll
        for (int c = 0; c < 2; ++c) {
            int k = ch * 512 + c * 256 + tid;
            float uc = fmaxf(usage[k], EPS);
            const float* er = es + (size_t)k * Dd;
            double a0 = 0, a1 = 0, a2 = 0, a3 = 0;
            for (int d = 0; d < Dd; d += 4) {
                a0 = fma((double)(er[d]     / uc), (double)xs[d],     a0);
                a1 = fma((double)(er[d + 1] / uc), (double)xs[d + 1], a1);
                a2 = fma((double)(er[d + 2] / uc), (double)xs[d + 2], a2);
                a3 = fma((double)(er[d + 3] / uc), (double)xs[d + 3], a3);
            }
            double s = fma(-2.0, (a0 + a1) + (a2 + a3), e2d[k]);
            if (s < bv || (s == bv && k < bi)) { bv = s; bi = k; }
        }
        sv[tid] = bv; si[tid] = bi;
        __syncthreads();
        for (int off = 128; off > 0; off >>= 1) {
            if (tid < off) {
                if (sv[tid + off] < sv[tid] ||
                    (sv[tid + off] == sv[tid] && si[tid + off] < si[tid])) {
                    sv[tid] = sv[tid + off]; si[tid] = si[tid + off];
                }
            }
            __syncthreads();
        }
        if (tid == 0) { fbv[task] = sv[0]; fbi[task] = si[0]; }
    }
}

__global__ void fmerge_kernel(const int* __restrict__ cnt,
                              const int* __restrict__ queueF,
                              const double* __restrict__ fbv,
                              const int* __restrict__ fbi,
                              float* __restrict__ out) {
    const int nF = cnt[1];
    for (int qi = blockIdx.x * 256 + threadIdx.x; qi < nF; qi += gridDim.x * 256) {
        double bv = DBL_MAX; int bi = 0x7fffffff;
        for (int c = 0; c < 16; ++c) {
            double v = fbv[qi * 16 + c]; int i = fbi[qi * 16 + c];
            if (v < bv || (v == bv && i < bi)) { bv = v; bi = i; }
        }
        out[queueF[qi]] = (float)bi;
    }
}

// ---------------- gather quantized rows, coalesced along t ------------------
__global__ __launch_bounds__(256) void gather_kernel(const float* __restrict__ es,
                                                     const float* __restrict__ usage,
                                                     float* __restrict__ out) {
    __shared__ int cs[64];
    __shared__ float us[64];
    const int tid = threadIdx.x;
    const int m0 = blockIdx.x * 64;
    const int b = m0 >> 10;
    const int t0 = m0 & (Tt - 1);
    if (tid < 64) {
        int c = (int)out[m0 + tid];
        cs[tid] = c;
        us[tid] = fmaxf(usage[c], EPS);
    }
    __syncthreads();
    const int tq = tid & 63;
    const int dg = tid >> 6;
    const int c = cs[tq];
    const float uc = us[tq];
    const float* row = es + (size_t)c * Dd;
    float* ob = out + Nq + (size_t)b * Dd * Tt + t0 + tq;
#pragma unroll 4
    for (int d = dg * 128; d < dg * 128 + 128; ++d)
        ob[(size_t)d * Tt] = row[d] / uc;       // fp32 div matches reference emb
}

extern "C" void kernel_launch(void* const* d_in, const int* in_sizes, int n_in,
                              void* d_out, int out_size, void* d_ws, size_t ws_size,
                              hipStream_t stream) {
    const float* x     = (const float*)d_in[0];
    const float* es    = (const float*)d_in[1];
    const float* usage = (const float*)d_in[2];
    float* out = (float*)d_out;

    char* w = (char*)d_ws;
    ushort* Xh = (ushort*)w;   w += (size_t)Nq * Dd * 2;      // 16 MB
    ushort* Xm = (ushort*)w;   w += (size_t)Nq * Dd * 2;      // 16 MB
    ushort* Eh = (ushort*)w;   w += (size_t)Kk * Dd * 2;      //  8 MB
    ushort* Em = (ushort*)w;   w += (size_t)Kk * Dd * 2;      //  8 MB
    double* e2d = (double*)w;  w += (size_t)Kk * 8;
    float*  e2f = (float*)w;   w += (size_t)Kk * 4;
    u64* colres = (u64*)w;     w += (size_t)Nq * 64 * 3 * 8;  // ~25 MB
    int* cnt = (int*)w;        w += 256;
    int* queueP = (int*)w;     w += (size_t)Nq * 3 * 4;
    int* queueF = (int*)w;     w += (size_t)Nq * 4;
    // fbv/fbi alias the Xh region: Xh/Xm are dead after gemm_kernel,
    // fscan/fmerge run strictly after merge_kernel on the same stream.
    double* fbv = (double*)Xh;                                // <=2 MB
    int*    fbi = (int*)((char*)Xh + 4 * 1024 * 1024);        // <=1 MB

    init_kernel<<<1, 64, 0, stream>>>(cnt);
    split_x_kernel<<<2048, 256, 0, stream>>>(x, Xh, Xm);
    split_e_kernel<<<Kk / 4, 256, 0, stream>>>(es, usage, Eh, Em, e2d, e2f);
    gemm_kernel<<<8192, 256, 0, stream>>>(Xh, Xm, Eh, Em, e2f, colres);
    merge_kernel<<<Nq / 4, 256, 0, stream>>>(colres, out, cnt, queueP, queueF);
    pair_kernel<<<32, 256, 0, stream>>>(x, es, usage, e2d, cnt, queueP, out);
    fscan_kernel<<<256, 256, 0, stream>>>(x, es, usage, e2d, cnt, queueF, fbv, fbi);
    fmerge_kernel<<<64, 256, 0, stream>>>(cnt, queueF, fbv, fbi, out);
    gather_kernel<<<Nq / 64, 256, 0, stream>>>(es, usage, out);
}

// Round 4
// 620.672 us; speedup vs baseline: 6.8217x; 1.0710x over previous
//
#include <hip/hip_runtime.h>
#include <hip/hip_bf16.h>
#include <cfloat>
#include <stdint.h>

#define EPS 1e-5f
constexpr int Dd = 512, Tt = 1024, Kk = 8192;
constexpr int Nq = 16 * 1024;
constexpr float TAU = 0.1f;   // > 2*split_err + key-quant (0.031); ~2x margin

typedef __bf16 bf16x8 __attribute__((ext_vector_type(8)));
typedef float  f32x4  __attribute__((ext_vector_type(4)));
typedef unsigned long long u64;

union Pack8 { __bf16 h[8]; int4 v; };

__device__ __forceinline__ void gld16(const void* g, void* l) {
    __builtin_amdgcn_global_load_lds(
        (const __attribute__((address_space(1))) uint32_t*)g,
        (__attribute__((address_space(3))) uint32_t*)l, 16, 0, 0);
}

// ---- monotone fp32 -> u32 key helpers --------------------------------------
__device__ __forceinline__ unsigned monokey(float s) {
    unsigned b = __float_as_uint(s);
    return b ^ ((unsigned)((int)b >> 31) | 0x80000000u);
}
__device__ __forceinline__ float unmono(unsigned u) {
    u = (u & 0x80000000u) ? (u ^ 0x80000000u) : ~u;
    return __uint_as_float(u);
}

__device__ __forceinline__ u64 umin64(u64 a, u64 b) { return a < b ? a : b; }
__device__ __forceinline__ u64 umax64(u64 a, u64 b) { return a > b ? a : b; }

__device__ __forceinline__ void merge3(u64& a1, u64& a2, u64& a3, u64 b1, u64 b2, u64 b3) {
    u64 c1 = umin64(a1, b1);
    u64 t  = umax64(a1, b1);
    u64 u  = umin64(a2, b2);
    u64 c2 = umin64(t, u);
    u64 c3 = umin64(umax64(t, u), umin64(a3, b3));
    a1 = c1; a2 = c2; a3 = c3;
}
__device__ __forceinline__ void merge3u(unsigned& a1, unsigned& a2, unsigned& a3,
                                        unsigned b1, unsigned b2, unsigned b3) {
    unsigned c1 = min(a1, b1);
    unsigned t  = max(a1, b1);
    unsigned u  = min(a2, b2);
    unsigned c2 = min(t, u);
    unsigned c3 = min(max(t, u), min(a3, b3));
    a1 = c1; a2 = c2; a3 = c3;
}

__device__ __forceinline__ u64 shflx64(u64 v, int m) {
    int lo = __shfl_xor((int)(unsigned)v, m, 64);
    int hi = __shfl_xor((int)(v >> 32), m, 64);
    return ((u64)(unsigned)hi << 32) | (unsigned)lo;
}

// ---------------- init: zero queue counters ---------------------------------
__global__ void init_kernel(int* cnt) {
    if (threadIdx.x == 0 && blockIdx.x == 0) { cnt[0] = 0; cnt[1] = 0; }
}

// ---------------- P1: x (B,D,T) -> Xh,Xm bf16 Dekker split ------------------
__global__ __launch_bounds__(256) void split_x_kernel(const float* __restrict__ x,
                                                      ushort* __restrict__ Xh,
                                                      ushort* __restrict__ Xm) {
    __shared__ float Ls[64][68];
    const int tid = threadIdx.x, bid = blockIdx.x;
    const int b  = bid >> 7;
    const int d0 = ((bid >> 4) & 7) * 64;
    const int t0 = (bid & 15) * 64;
    const float* xb = x + ((size_t)b * Dd + d0) * Tt + t0;
#pragma unroll
    for (int it = 0; it < 4; ++it) {
        int s = it * 256 + tid;
        int d = s >> 4, c = (s & 15) * 4;
        float4 g = *(const float4*)(xb + (size_t)d * Tt + c);
        *(float4*)&Ls[d][c] = g;
    }
    __syncthreads();
    const int t = tid >> 2;
    const int dseg = (tid & 3) * 16;
    Pack8 ph[2], pm[2];
#pragma unroll
    for (int dd = 0; dd < 16; ++dd) {
        float v = Ls[dseg + dd][t];
        __bf16 h = (__bf16)v;
        __bf16 m = (__bf16)(v - (float)h);
        ph[dd >> 3].h[dd & 7] = h;
        pm[dd >> 3].h[dd & 7] = m;
    }
    size_t base = ((size_t)(b * Tt + t0 + t)) * Dd + d0 + dseg;
    *(int4*)(Xh + base)     = ph[0].v;
    *(int4*)(Xh + base + 8) = ph[1].v;
    *(int4*)(Xm + base)     = pm[0].v;
    *(int4*)(Xm + base + 8) = pm[1].v;
}

// ---------------- P2: emb=es/clip(u) -> Eh,Em bf16 split + e2 ---------------
__global__ __launch_bounds__(256) void split_e_kernel(const float* __restrict__ es,
                                                      const float* __restrict__ usage,
                                                      ushort* __restrict__ Eh,
                                                      ushort* __restrict__ Em,
                                                      double* __restrict__ e2d,
                                                      float* __restrict__ e2f) {
    const int wave = threadIdx.x >> 6, lane = threadIdx.x & 63;
    const int k = blockIdx.x * 4 + wave;
    const float uc = fmaxf(usage[k], EPS);
    const float* row = es + (size_t)k * Dd;
    const int d = lane * 8;
    float4 a = *(const float4*)(row + d);
    float4 c = *(const float4*)(row + d + 4);
    float ef[8] = {a.x/uc, a.y/uc, a.z/uc, a.w/uc, c.x/uc, c.y/uc, c.z/uc, c.w/uc};
    Pack8 ph, pm;
    double e2 = 0.0;
#pragma unroll
    for (int j = 0; j < 8; ++j) {
        __bf16 h = (__bf16)ef[j];
        __bf16 m = (__bf16)(ef[j] - (float)h);
        ph.h[j] = h; pm.h[j] = m;
        e2 = fma((double)ef[j], (double)ef[j], e2);
    }
    size_t base = (size_t)k * Dd + d;
    *(int4*)(Eh + base) = ph.v;
    *(int4*)(Em + base) = pm.v;
#pragma unroll
    for (int off = 32; off >= 1; off >>= 1) e2 += __shfl_down(e2, off, 64);
    if (lane == 0) { e2d[k] = e2; e2f[k] = (float)e2; }
}

// ---------------- main GEMM: 128x128, swizzled LDS, u32-key top-3 epilogue --
__global__ __launch_bounds__(256) void gemm_kernel(const ushort* __restrict__ Xh,
                                                   const ushort* __restrict__ Xm,
                                                   const ushort* __restrict__ Eh,
                                                   const ushort* __restrict__ Em,
                                                   const float* __restrict__ e2f,
                                                   unsigned* __restrict__ colres) {
    __shared__ ushort Ahs[128 * 32], Ams[128 * 32], Bhs[128 * 32], Bms[128 * 32];
    __shared__ unsigned trip[2][128][3];

    const int tid = threadIdx.x;
    const int nb = blockIdx.x & 63, mb = blockIdx.x >> 6;
    const int m0 = mb * 128, n0 = nb * 128;
    const int wave = tid >> 6, lane = tid & 63;
    const int mw = (wave >> 1) * 64, nw = (wave & 1) * 64;
    const int fm = lane & 15, fq = lane >> 4;
    const int sw = (fm >> 1) & 3;                 // read-side XOR swizzle
    const int cphys = (fq ^ sw) * 8;

    f32x4 acc[4][4] = {};

    for (int d0 = 0; d0 < Dd; d0 += 32) {
#pragma unroll
        for (int j = 0; j < 2; ++j) {
            int s = j * 256 + tid;
            int r = s >> 2;
            int c = ((s & 3) ^ ((s >> 3) & 3)) * 8;  // store-side swizzle
            size_t ga = (size_t)(m0 + r) * Dd + d0 + c;
            size_t gb = (size_t)(n0 + r) * Dd + d0 + c;
            gld16(Xh + ga, (char*)Ahs + s * 16);
            gld16(Xm + ga, (char*)Ams + s * 16);
            gld16(Eh + gb, (char*)Bhs + s * 16);
            gld16(Em + gb, (char*)Bms + s * 16);
        }
        __syncthreads();
        bf16x8 ah[4], am[4], bh[4], bm[4];
#pragma unroll
        for (int i = 0; i < 4; ++i) {
            int ra = (mw + i * 16 + fm) * 32 + cphys;
            int rb = (nw + i * 16 + fm) * 32 + cphys;
            ah[i] = *(const bf16x8*)&Ahs[ra];
            am[i] = *(const bf16x8*)&Ams[ra];
            bh[i] = *(const bf16x8*)&Bhs[rb];
            bm[i] = *(const bf16x8*)&Bms[rb];
        }
#pragma unroll
        for (int i = 0; i < 4; ++i)
#pragma unroll
            for (int j = 0; j < 4; ++j) {
                acc[i][j] = __builtin_amdgcn_mfma_f32_16x16x32_bf16(ah[i], bh[j], acc[i][j], 0, 0, 0);
                acc[i][j] = __builtin_amdgcn_mfma_f32_16x16x32_bf16(ah[i], bm[j], acc[i][j], 0, 0, 0);
                acc[i][j] = __builtin_amdgcn_mfma_f32_16x16x32_bf16(am[i], bh[j], acc[i][j], 0, 0, 0);
            }
        __syncthreads();
    }

    float e2r[4];
#pragma unroll
    for (int j = 0; j < 4; ++j) e2r[j] = e2f[n0 + nw + j * 16 + fm];

    // top-3 per (row, 128-col block) with u32 keys (low 7 bits = col-in-block)
#pragma unroll
    for (int i = 0; i < 4; ++i)
#pragma unroll
        for (int r = 0; r < 4; ++r) {
            unsigned k[4];
#pragma unroll
            for (int j = 0; j < 4; ++j) {
                float s = fmaf(-2.0f, acc[i][j][r], e2r[j]);
                k[j] = (monokey(s) & 0xFFFFFF80u) | (unsigned)(nw + j * 16 + fm);
            }
            unsigned p  = min(k[0], k[1]), q  = max(k[0], k[1]);
            unsigned rr = min(k[2], k[3]), t  = max(k[2], k[3]);
            unsigned a1 = min(p, rr), b2 = max(p, rr);
            unsigned m1 = min(q, t),  M1 = max(q, t);
            unsigned a2 = min(b2, m1);
            unsigned a3 = min(max(b2, m1), M1);
#pragma unroll
            for (int st = 1; st < 16; st <<= 1) {
                unsigned s1 = __shfl_xor(a1, st, 64);
                unsigned s2 = __shfl_xor(a2, st, 64);
                unsigned s3 = __shfl_xor(a3, st, 64);
                merge3u(a1, a2, a3, s1, s2, s3);
            }
            if (fm == 0) {
                int rl = mw + i * 16 + fq * 4 + r;
                trip[wave & 1][rl][0] = a1;
                trip[wave & 1][rl][1] = a2;
                trip[wave & 1][rl][2] = a3;
            }
        }
    __syncthreads();
    if (tid < 128) {
        unsigned a1 = trip[0][tid][0], a2 = trip[0][tid][1], a3 = trip[0][tid][2];
        merge3u(a1, a2, a3, trip[1][tid][0], trip[1][tid][1], trip[1][tid][2]);
        size_t o = ((size_t)(m0 + tid) * 64 + nb) * 3;
        colres[o] = a1; colres[o + 1] = a2; colres[o + 2] = a3;
    }
}

// ---------------- merge 64 col-blocks -> global top-3; tiered flagging ------
__global__ __launch_bounds__(256) void merge_kernel(const unsigned* __restrict__ colres,
                                                    float* __restrict__ out,
                                                    int* __restrict__ cnt,
                                                    int* __restrict__ queueP,
                                                    int* __restrict__ queueF) {
    const int wave = threadIdx.x >> 6, lane = threadIdx.x & 63;
    const int row = blockIdx.x * 4 + wave;
    size_t o = ((size_t)row * 64 + lane) * 3;
    unsigned k1 = colres[o], k2 = colres[o + 1], k3 = colres[o + 2];
    const unsigned nb128 = (unsigned)(lane * 128);
    u64 a1 = ((u64)(k1 & 0xFFFFFF80u) << 32) | (nb128 + (k1 & 127u));
    u64 a2 = ((u64)(k2 & 0xFFFFFF80u) << 32) | (nb128 + (k2 & 127u));
    u64 a3 = ((u64)(k3 & 0xFFFFFF80u) << 32) | (nb128 + (k3 & 127u));
#pragma unroll
    for (int st = 1; st < 64; st <<= 1)
        merge3(a1, a2, a3, shflx64(a1, st), shflx64(a2, st), shflx64(a3, st));
    if (lane == 0) {
        float v1 = unmono((unsigned)(a1 >> 32));
        float v2 = unmono((unsigned)(a2 >> 32));
        float v3 = unmono((unsigned)(a3 >> 32));
        int i1 = (int)(unsigned)a1, i2 = (int)(unsigned)a2;
        out[row] = (float)i1;
        if (v3 - v1 < TAU) {                    // possible hidden 3rd: full scan
            int p = atomicAdd(&cnt[1], 1);
            queueF[p] = row;
        } else if (v2 - v1 < TAU) {             // winner provably in {i1,i2}
            int p = atomicAdd(&cnt[0], 1);
            queueP[p * 3] = row; queueP[p * 3 + 1] = i1; queueP[p * 3 + 2] = i2;
        }
    }
}

// ---------------- pair rescore: exact fp64 on {i1,i2}, one wave per query ---
__global__ __launch_bounds__(256) void pair_kernel(const float* __restrict__ x,
                                                   const float* __restrict__ es,
                                                   const float* __restrict__ usage,
                                                   const double* __restrict__ e2d,
                                                   const int* __restrict__ cnt,
                                                   const int* __restrict__ queueP,
                                                   float* __restrict__ out) {
    const int wv = (blockIdx.x << 2) | (threadIdx.x >> 6);
    const int lane = threadIdx.x & 63;
    const int n = cnt[0];
    for (int p = wv; p < n; p += gridDim.x * 4) {
        int row = queueP[p * 3], i1 = queueP[p * 3 + 1], i2 = queueP[p * 3 + 2];
        int b = row >> 10, t = row & 1023;
        const float* xb = x + (size_t)b * Dd * Tt + t;
        float uc1 = fmaxf(usage[i1], EPS), uc2 = fmaxf(usage[i2], EPS);
        const float* e1 = es + (size_t)i1 * Dd + lane * 8;
        const float* e2 = es + (size_t)i2 * Dd + lane * 8;
        double s1 = 0.0, s2 = 0.0;
#pragma unroll
        for (int j = 0; j < 8; ++j) {
            double xv = (double)xb[(size_t)(lane * 8 + j) * Tt];
            s1 = fma(xv, (double)(e1[j] / uc1), s1);
            s2 = fma(xv, (double)(e2[j] / uc2), s2);
        }
#pragma unroll
        for (int off = 32; off >= 1; off >>= 1) {
            s1 += __shfl_down(s1, off, 64);
            s2 += __shfl_down(s2, off, 64);
        }
        if (lane == 0) {
            double d1 = fma(-2.0, s1, e2d[i1]);
            double d2 = fma(-2.0, s2, e2d[i2]);
            int c = (d2 < d1 || (d2 == d1 && i2 < i1)) ? i2 : i1;
            out[row] = (float)c;
        }
    }
}

// ---------------- rare full exact scan: 16 chunks x 512 clusters per query --
__global__ __launch_bounds__(256) void fscan_kernel(const float* __restrict__ x,
                                                    const float* __restrict__ es,
                                                    const float* __restrict__ usage,
                                                    const double* __restrict__ e2d,
                                                    const int* __restrict__ cnt,
                                                    const int* __restrict__ queueF,
                                                    double* __restrict__ fbv,
                                                    int* __restrict__ fbi) {
    __shared__ float xs[512];
    __shared__ double sv[256];
    __shared__ int si[256];
    const int tid = threadIdx.x;
    const int ntask = cnt[1] * 16;
    for (int task = blockIdx.x; task < ntask; task += gridDim.x) {
        int qi = task >> 4, ch = task & 15;
        int row = queueF[qi];
        int b = row >> 10, t = row & 1023;
        __syncthreads();
        for (int d = tid; d < Dd; d += 256)
            xs[d] = x[((size_t)b * Dd + d) * Tt + t];
        __syncthreads();
        double bv = DBL_MAX; int bi = 0x7fffffff;
#pragma unroll
        for (int c = 0; c < 2; ++c) {
            int k = ch * 512 + c * 256 + tid;
            float uc = fmaxf(usage[k], EPS);
            const float* er = es + (size_t)k * Dd;
            double a0 = 0, a1 = 0, a2 = 0, a3 = 0;
            for (int d = 0; d < Dd; d += 4) {
                a0 = fma((double)(er[d]     / uc), (double)xs[d],     a0);
                a1 = fma((double)(er[d + 1] / uc), (double)xs[d + 1], a1);
                a2 = fma((double)(er[d + 2] / uc), (double)xs[d + 2], a2);
                a3 = fma((double)(er[d + 3] / uc), (double)xs[d + 3], a3);
            }
            double s = fma(-2.0, (a0 + a1) + (a2 + a3), e2d[k]);
            if (s < bv || (s == bv && k < bi)) { bv = s; bi = k; }
        }
        sv[tid] = bv; si[tid] = bi;
        __syncthreads();
        for (int off = 128; off > 0; off >>= 1) {
            if (tid < off) {
                if (sv[tid + off] < sv[tid] ||
                    (sv[tid + off] == sv[tid] && si[tid + off] < si[tid])) {
                    sv[tid] = sv[tid + off]; si[tid] = si[tid + off];
                }
            }
            __syncthreads();
        }
        if (tid == 0) { fbv[task] = sv[0]; fbi[task] = si[0]; }
    }
}

__global__ void fmerge_kernel(const int* __restrict__ cnt,
                              const int* __restrict__ queueF,
                              const double* __restrict__ fbv,
                              const int* __restrict__ fbi,
                              float* __restrict__ out) {
    const int nF = cnt[1];
    for (int qi = blockIdx.x * 256 + threadIdx.x; qi < nF; qi += gridDim.x * 256) {
        double bv = DBL_MAX; int bi = 0x7fffffff;
        for (int c = 0; c < 16; ++c) {
            double v = fbv[qi * 16 + c]; int i = fbi[qi * 16 + c];
            if (v < bv || (v == bv && i < bi)) { bv = v; bi = i; }
        }
        out[queueF[qi]] = (float)bi;
    }
}

// ---------------- gather quantized rows, coalesced along t ------------------
__global__ __launch_bounds__(256) void gather_kernel(const float* __restrict__ es,
                                                     const float* __restrict__ usage,
                                                     float* __restrict__ out) {
    __shared__ int cs[64];
    __shared__ float us[64];
    const int tid = threadIdx.x;
    const int m0 = blockIdx.x * 64;
    const int b = m0 >> 10;
    const int t0 = m0 & (Tt - 1);
    if (tid < 64) {
        int c = (int)out[m0 + tid];
        cs[tid] = c;
        us[tid] = fmaxf(usage[c], EPS);
    }
    __syncthreads();
    const int tq = tid & 63;
    const int dg = tid >> 6;
    const int c = cs[tq];
    const float uc = us[tq];
    const float* row = es + (size_t)c * Dd;
    float* ob = out + Nq + (size_t)b * Dd * Tt + t0 + tq;
#pragma unroll 4
    for (int d = dg * 128; d < dg * 128 + 128; ++d)
        ob[(size_t)d * Tt] = row[d] / uc;
}

extern "C" void kernel_launch(void* const* d_in, const int* in_sizes, int n_in,
                              void* d_out, int out_size, void* d_ws, size_t ws_size,
                              hipStream_t stream) {
    const float* x     = (const float*)d_in[0];
    const float* es    = (const float*)d_in[1];
    const float* usage = (const float*)d_in[2];
    float* out = (float*)d_out;

    char* w = (char*)d_ws;
    ushort* Xh = (ushort*)w;   w += (size_t)Nq * Dd * 2;      // 16 MB
    ushort* Xm = (ushort*)w;   w += (size_t)Nq * Dd * 2;      // 16 MB
    ushort* Eh = (ushort*)w;   w += (size_t)Kk * Dd * 2;      //  8 MB
    ushort* Em = (ushort*)w;   w += (size_t)Kk * Dd * 2;      //  8 MB
    double* e2d = (double*)w;  w += (size_t)Kk * 8;
    float*  e2f = (float*)w;   w += (size_t)Kk * 4;
    unsigned* colres = (unsigned*)w; w += (size_t)Nq * 64 * 3 * 4;  // ~12.6 MB
    int* cnt = (int*)w;        w += 256;
    int* queueP = (int*)w;     w += (size_t)Nq * 3 * 4;
    int* queueF = (int*)w;     w += (size_t)Nq * 4;
    // fbv/fbi alias Xh (dead after gemm_kernel; fscan runs strictly later)
    double* fbv = (double*)Xh;
    int*    fbi = (int*)((char*)Xh + 4 * 1024 * 1024);

    init_kernel<<<1, 64, 0, stream>>>(cnt);
    split_x_kernel<<<2048, 256, 0, stream>>>(x, Xh, Xm);
    split_e_kernel<<<Kk / 4, 256, 0, stream>>>(es, usage, Eh, Em, e2d, e2f);
    gemm_kernel<<<8192, 256, 0, stream>>>(Xh, Xm, Eh, Em, e2f, colres);
    merge_kernel<<<Nq / 4, 256, 0, stream>>>(colres, out, cnt, queueP, queueF);
    pair_kernel<<<64, 256, 0, stream>>>(x, es, usage, e2d, cnt, queueP, out);
    fscan_kernel<<<256, 256, 0, stream>>>(x, es, usage, e2d, cnt, queueF, fbv, fbi);
    fmerge_kernel<<<64, 256, 0, stream>>>(cnt, queueF, fbv, fbi, out);
    gather_kernel<<<Nq / 64, 256, 0, stream>>>(es, usage, out);
}

// Round 5
// 537.477 us; speedup vs baseline: 7.8776x; 1.1548x over previous
//
#include <hip/hip_runtime.h>
#include <hip/hip_bf16.h>
#include <cfloat>
#include <stdint.h>

#define EPS 1e-5f
constexpr int Dd = 512, Tt = 1024, Kk = 8192;
constexpr int Nq = 16 * 1024;
constexpr float TAU = 1.5f;   // >=6 sigma of dropped xm*eh term + key quant

typedef __bf16 bf16x8 __attribute__((ext_vector_type(8)));
typedef float  f32x4  __attribute__((ext_vector_type(4)));
typedef unsigned long long u64;

union Pack8 { __bf16 h[8]; int4 v; };

__device__ __forceinline__ void gld16(const void* g, void* l) {
    __builtin_amdgcn_global_load_lds(
        (const __attribute__((address_space(1))) uint32_t*)g,
        (__attribute__((address_space(3))) uint32_t*)l, 16, 0, 0);
}

// ---- monotone fp32 -> u32 key helpers --------------------------------------
__device__ __forceinline__ unsigned monokey(float s) {
    unsigned b = __float_as_uint(s);
    return b ^ ((unsigned)((int)b >> 31) | 0x80000000u);
}
__device__ __forceinline__ float unmono(unsigned u) {
    u = (u & 0x80000000u) ? (u ^ 0x80000000u) : ~u;
    return __uint_as_float(u);
}

// ---- sorted-quad merge (keep smallest 4 of two sorted quads) ---------------
__device__ __forceinline__ void merge4u(unsigned& a1, unsigned& a2, unsigned& a3, unsigned& a4,
                                        unsigned b1, unsigned b2, unsigned b3, unsigned b4) {
    unsigned c1 = min(a1, b1);
    unsigned c2 = min(min(a2, b2), max(a1, b1));
    unsigned c3 = min(min(a3, b3), min(max(a2, b1), max(a1, b2)));
    unsigned c4 = min(min(a4, b4), min(max(a3, b1), max(a1, b3)));
    c4 = min(c4, max(a2, b2));
    a1 = c1; a2 = c2; a3 = c3; a4 = c4;
}
__device__ __forceinline__ u64 umin64(u64 a, u64 b) { return a < b ? a : b; }
__device__ __forceinline__ u64 umax64(u64 a, u64 b) { return a > b ? a : b; }
__device__ __forceinline__ void merge4q(u64& a1, u64& a2, u64& a3, u64& a4,
                                        u64 b1, u64 b2, u64 b3, u64 b4) {
    u64 c1 = umin64(a1, b1);
    u64 c2 = umin64(umin64(a2, b2), umax64(a1, b1));
    u64 c3 = umin64(umin64(a3, b3), umin64(umax64(a2, b1), umax64(a1, b2)));
    u64 c4 = umin64(umin64(a4, b4), umin64(umax64(a3, b1), umax64(a1, b3)));
    c4 = umin64(c4, umax64(a2, b2));
    a1 = c1; a2 = c2; a3 = c3; a4 = c4;
}
__device__ __forceinline__ u64 shflx64(u64 v, int m) {
    int lo = __shfl_xor((int)(unsigned)v, m, 64);
    int hi = __shfl_xor((int)(v >> 32), m, 64);
    return ((u64)(unsigned)hi << 32) | (unsigned)lo;
}

// ---------------- init: zero queue counters ---------------------------------
__global__ void init_kernel(int* cnt) {
    if (threadIdx.x == 0 && blockIdx.x == 0) { cnt[0] = 0; cnt[1] = 0; }
}

// ---------------- P1: x (B,D,T) -> Xh (B*T, D) bf16 head only ---------------
__global__ __launch_bounds__(256) void split_x_kernel(const float* __restrict__ x,
                                                      ushort* __restrict__ Xh) {
    __shared__ float Ls[64][68];
    const int tid = threadIdx.x, bid = blockIdx.x;
    const int b  = bid >> 7;
    const int d0 = ((bid >> 4) & 7) * 64;
    const int t0 = (bid & 15) * 64;
    const float* xb = x + ((size_t)b * Dd + d0) * Tt + t0;
#pragma unroll
    for (int it = 0; it < 4; ++it) {
        int s = it * 256 + tid;
        int d = s >> 4, c = (s & 15) * 4;
        float4 g = *(const float4*)(xb + (size_t)d * Tt + c);
        *(float4*)&Ls[d][c] = g;
    }
    __syncthreads();
    const int t = tid >> 2;
    const int dseg = (tid & 3) * 16;
    Pack8 ph[2];
#pragma unroll
    for (int dd = 0; dd < 16; ++dd) {
        float v = Ls[dseg + dd][t];
        ph[dd >> 3].h[dd & 7] = (__bf16)v;
    }
    size_t base = ((size_t)(b * Tt + t0 + t)) * Dd + d0 + dseg;
    *(int4*)(Xh + base)     = ph[0].v;
    *(int4*)(Xh + base + 8) = ph[1].v;
}

// ---------------- P2: emb=es/clip(u) -> Eh,Em split + embf fp32 + e2 --------
__global__ __launch_bounds__(256) void split_e_kernel(const float* __restrict__ es,
                                                      const float* __restrict__ usage,
                                                      ushort* __restrict__ Eh,
                                                      ushort* __restrict__ Em,
                                                      float* __restrict__ embf,
                                                      double* __restrict__ e2d,
                                                      float* __restrict__ e2f) {
    const int wave = threadIdx.x >> 6, lane = threadIdx.x & 63;
    const int k = blockIdx.x * 4 + wave;
    const float uc = fmaxf(usage[k], EPS);
    const float* row = es + (size_t)k * Dd;
    const int d = lane * 8;
    float4 a = *(const float4*)(row + d);
    float4 c = *(const float4*)(row + d + 4);
    float ef[8] = {a.x/uc, a.y/uc, a.z/uc, a.w/uc, c.x/uc, c.y/uc, c.z/uc, c.w/uc};
    Pack8 ph, pm;
    double e2 = 0.0;
#pragma unroll
    for (int j = 0; j < 8; ++j) {
        __bf16 h = (__bf16)ef[j];
        __bf16 m = (__bf16)(ef[j] - (float)h);   // exact Dekker residual
        ph.h[j] = h; pm.h[j] = m;
        e2 = fma((double)ef[j], (double)ef[j], e2);
    }
    size_t base = (size_t)k * Dd + d;
    *(int4*)(Eh + base) = ph.v;
    *(int4*)(Em + base) = pm.v;
    *(float4*)(embf + base)     = make_float4(ef[0], ef[1], ef[2], ef[3]);
    *(float4*)(embf + base + 4) = make_float4(ef[4], ef[5], ef[6], ef[7]);
#pragma unroll
    for (int off = 32; off >= 1; off >>= 1) e2 += __shfl_down(e2, off, 64);
    if (lane == 0) { e2d[k] = e2; e2f[k] = (float)e2; }
}

// ---------------- main GEMM: 128x128, 2-product split, top-4 epilogue -------
__global__ __launch_bounds__(256) void gemm_kernel(const ushort* __restrict__ Xh,
                                                   const ushort* __restrict__ Eh,
                                                   const ushort* __restrict__ Em,
                                                   const float* __restrict__ e2f,
                                                   uint4* __restrict__ colres) {
    __shared__ ushort Ahs[128 * 32], Bhs[128 * 32], Bms[128 * 32];
    __shared__ unsigned trip[2][128][4];

    const int tid = threadIdx.x;
    const int nb = blockIdx.x & 63, mb = blockIdx.x >> 6;
    const int m0 = mb * 128, n0 = nb * 128;
    const int wave = tid >> 6, lane = tid & 63;
    const int mw = (wave >> 1) * 64, nw = (wave & 1) * 64;
    const int fm = lane & 15, fq = lane >> 4;
    const int cphys = (fq ^ ((fm >> 1) & 3)) * 8;   // read-side XOR swizzle

    f32x4 acc[4][4] = {};

    for (int d0 = 0; d0 < Dd; d0 += 32) {
#pragma unroll
        for (int j = 0; j < 2; ++j) {
            int s = j * 256 + tid;
            int r = s >> 2;
            int c = ((s & 3) ^ ((s >> 3) & 3)) * 8;  // store-side swizzle
            size_t ga = (size_t)(m0 + r) * Dd + d0 + c;
            size_t gb = (size_t)(n0 + r) * Dd + d0 + c;
            gld16(Xh + ga, (char*)Ahs + s * 16);
            gld16(Eh + gb, (char*)Bhs + s * 16);
            gld16(Em + gb, (char*)Bms + s * 16);
        }
        __syncthreads();
        bf16x8 ah[4], bh[4], bm[4];
#pragma unroll
        for (int i = 0; i < 4; ++i) {
            int ra = (mw + i * 16 + fm) * 32 + cphys;
            int rb = (nw + i * 16 + fm) * 32 + cphys;
            ah[i] = *(const bf16x8*)&Ahs[ra];
            bh[i] = *(const bf16x8*)&Bhs[rb];
            bm[i] = *(const bf16x8*)&Bms[rb];
        }
#pragma unroll
        for (int i = 0; i < 4; ++i)
#pragma unroll
            for (int j = 0; j < 4; ++j) {
                acc[i][j] = __builtin_amdgcn_mfma_f32_16x16x32_bf16(ah[i], bh[j], acc[i][j], 0, 0, 0);
                acc[i][j] = __builtin_amdgcn_mfma_f32_16x16x32_bf16(ah[i], bm[j], acc[i][j], 0, 0, 0);
            }
        __syncthreads();
    }

    float e2r[4];
#pragma unroll
    for (int j = 0; j < 4; ++j) e2r[j] = e2f[n0 + nw + j * 16 + fm];

    // top-4 per (row, 128-col block); u32 keys, low 7 bits = col-in-block
#pragma unroll
    for (int i = 0; i < 4; ++i)
#pragma unroll
        for (int r = 0; r < 4; ++r) {
            unsigned k[4];
#pragma unroll
            for (int j = 0; j < 4; ++j) {
                float s = fmaf(-2.0f, acc[i][j][r], e2r[j]);
                k[j] = (monokey(s) & 0xFFFFFF80u) | (unsigned)(nw + j * 16 + fm);
            }
            unsigned lo01 = min(k[0], k[1]), hi01 = max(k[0], k[1]);
            unsigned lo23 = min(k[2], k[3]), hi23 = max(k[2], k[3]);
            unsigned a1 = min(lo01, lo23), t3 = max(lo01, lo23);
            unsigned t2 = min(hi01, hi23), a4 = max(hi01, hi23);
            unsigned a2 = min(t3, t2), a3 = max(t3, t2);
#pragma unroll
            for (int st = 1; st < 16; st <<= 1) {
                unsigned b1 = __shfl_xor(a1, st, 64);
                unsigned b2 = __shfl_xor(a2, st, 64);
                unsigned b3 = __shfl_xor(a3, st, 64);
                unsigned b4 = __shfl_xor(a4, st, 64);
                merge4u(a1, a2, a3, a4, b1, b2, b3, b4);
            }
            if (fm == 0) {
                int rl = mw + i * 16 + fq * 4 + r;
                trip[wave & 1][rl][0] = a1;
                trip[wave & 1][rl][1] = a2;
                trip[wave & 1][rl][2] = a3;
                trip[wave & 1][rl][3] = a4;
            }
        }
    __syncthreads();
    if (tid < 128) {
        unsigned a1 = trip[0][tid][0], a2 = trip[0][tid][1];
        unsigned a3 = trip[0][tid][2], a4 = trip[0][tid][3];
        merge4u(a1, a2, a3, a4,
                trip[1][tid][0], trip[1][tid][1], trip[1][tid][2], trip[1][tid][3]);
        colres[(size_t)(m0 + tid) * 64 + nb] = make_uint4(a1, a2, a3, a4);
    }
}

// ---------------- merge 64 col-blocks -> global top-4; tiered flagging ------
__global__ __launch_bounds__(256) void merge_kernel(const uint4* __restrict__ colres,
                                                    float* __restrict__ out,
                                                    int* __restrict__ cnt,
                                                    int* __restrict__ queueC,
                                                    int* __restrict__ queueF) {
    const int wave = threadIdx.x >> 6, lane = threadIdx.x & 63;
    const int row = blockIdx.x * 4 + wave;
    uint4 q = colres[(size_t)row * 64 + lane];
    const unsigned nb128 = (unsigned)(lane * 128);
    u64 a1 = ((u64)(q.x & 0xFFFFFF80u) << 32) | (nb128 + (q.x & 127u));
    u64 a2 = ((u64)(q.y & 0xFFFFFF80u) << 32) | (nb128 + (q.y & 127u));
    u64 a3 = ((u64)(q.z & 0xFFFFFF80u) << 32) | (nb128 + (q.z & 127u));
    u64 a4 = ((u64)(q.w & 0xFFFFFF80u) << 32) | (nb128 + (q.w & 127u));
#pragma unroll
    for (int st = 1; st < 64; st <<= 1)
        merge4q(a1, a2, a3, a4, shflx64(a1, st), shflx64(a2, st), shflx64(a3, st), shflx64(a4, st));
    if (lane == 0) {
        float v1 = unmono((unsigned)(a1 >> 32));
        float v2 = unmono((unsigned)(a2 >> 32));
        float v4 = unmono((unsigned)(a4 >> 32));
        int i1 = (int)(unsigned)a1, i2 = (int)(unsigned)a2, i3 = (int)(unsigned)a3;
        out[row] = (float)i1;
        if (v4 - v1 < TAU) {                    // winner may be outside top-4
            int p = atomicAdd(&cnt[1], 1);
            queueF[p] = row;
        } else if (v2 - v1 < TAU) {             // winner provably in {i1,i2,i3}
            int p = atomicAdd(&cnt[0], 1);
            queueC[p * 4] = row; queueC[p * 4 + 1] = i1;
            queueC[p * 4 + 2] = i2; queueC[p * 4 + 3] = i3;
        }
    }
}

// ---------------- candidate rescore: exact fp64 on {i1,i2,i3} ---------------
__global__ __launch_bounds__(256) void cand_kernel(const float* __restrict__ x,
                                                   const float* __restrict__ embf,
                                                   const double* __restrict__ e2d,
                                                   const int* __restrict__ cnt,
                                                   const int* __restrict__ queueC,
                                                   float* __restrict__ out) {
    const int wv = (blockIdx.x << 2) | (threadIdx.x >> 6);
    const int lane = threadIdx.x & 63;
    const int n = cnt[0];
    for (int p = wv; p < n; p += gridDim.x * 4) {
        int row = queueC[p * 4];
        int ci[3] = {queueC[p * 4 + 1], queueC[p * 4 + 2], queueC[p * 4 + 3]};
        int b = row >> 10, t = row & 1023;
        const float* xb = x + (size_t)b * Dd * Tt + t;
        const int d0 = lane * 8;
        const float* e0 = embf + (size_t)ci[0] * Dd + d0;
        const float* e1 = embf + (size_t)ci[1] * Dd + d0;
        const float* e2 = embf + (size_t)ci[2] * Dd + d0;
        double s0 = 0.0, s1 = 0.0, s2 = 0.0;
#pragma unroll
        for (int j = 0; j < 8; ++j) {
            double xv = (double)xb[(size_t)(d0 + j) * Tt];
            s0 = fma(xv, (double)e0[j], s0);
            s1 = fma(xv, (double)e1[j], s1);
            s2 = fma(xv, (double)e2[j], s2);
        }
#pragma unroll
        for (int off = 32; off >= 1; off >>= 1) {
            s0 += __shfl_down(s0, off, 64);
            s1 += __shfl_down(s1, off, 64);
            s2 += __shfl_down(s2, off, 64);
        }
        if (lane == 0) {
            double dv[3] = {fma(-2.0, s0, e2d[ci[0]]),
                            fma(-2.0, s1, e2d[ci[1]]),
                            fma(-2.0, s2, e2d[ci[2]])};
            double bv = dv[0]; int bi = ci[0];
#pragma unroll
            for (int c = 1; c < 3; ++c)
                if (dv[c] < bv || (dv[c] == bv && ci[c] < bi)) { bv = dv[c]; bi = ci[c]; }
            out[row] = (float)bi;
        }
    }
}

// ---------------- rare full exact scan: 16 chunks x 512 clusters per query --
__global__ __launch_bounds__(256) void fscan_kernel(const float* __restrict__ x,
                                                    const float* __restrict__ embf,
                                                    const double* __restrict__ e2d,
                                                    const int* __restrict__ cnt,
                                                    const int* __restrict__ queueF,
                                                    double* __restrict__ fbv,
                                                    int* __restrict__ fbi) {
    __shared__ float xs[512];
    __shared__ double sv[256];
    __shared__ int si[256];
    const int tid = threadIdx.x;
    const int ntask = cnt[1] * 16;
    for (int task = blockIdx.x; task < ntask; task += gridDim.x) {
        int qi = task >> 4, ch = task & 15;
        int row = queueF[qi];
        int b = row >> 10, t = row & 1023;
        __syncthreads();
        for (int d = tid; d < Dd; d += 256)
            xs[d] = x[((size_t)b * Dd + d) * Tt + t];
        __syncthreads();
        double bv = DBL_MAX; int bi = 0x7fffffff;
#pragma unroll
        for (int c = 0; c < 2; ++c) {
            int k = ch * 512 + c * 256 + tid;
            const float* er = embf + (size_t)k * Dd;
            double a0 = 0, a1 = 0, a2 = 0, a3 = 0;
            for (int d = 0; d < Dd; d += 4) {
                float4 e = *(const float4*)(er + d);
                float4 xv = *(const float4*)&xs[d];
                a0 = fma((double)e.x, (double)xv.x, a0);
                a1 = fma((double)e.y, (double)xv.y, a1);
                a2 = fma((double)e.z, (double)xv.z, a2);
                a3 = fma((double)e.w, (double)xv.w, a3);
            }
            double s = fma(-2.0, (a0 + a1) + (a2 + a3), e2d[k]);
            if (s < bv || (s == bv && k < bi)) { bv = s; bi = k; }
        }
        sv[tid] = bv; si[tid] = bi;
        __syncthreads();
        for (int off = 128; off > 0; off >>= 1) {
            if (tid < off) {
                if (sv[tid + off] < sv[tid] ||
                    (sv[tid + off] == sv[tid] && si[tid + off] < si[tid])) {
                    sv[tid] = sv[tid + off]; si[tid] = si[tid + off];
                }
            }
            __syncthreads();
        }
        if (tid == 0) { fbv[task] = sv[0]; fbi[task] = si[0]; }
    }
}

__global__ void fmerge_kernel(const int* __restrict__ cnt,
                              const int* __restrict__ queueF,
                              const double* __restrict__ fbv,
                              const int* __restrict__ fbi,
                              float* __restrict__ out) {
    const int nF = cnt[1];
    for (int qi = blockIdx.x * 256 + threadIdx.x; qi < nF; qi += gridDim.x * 256) {
        double bv = DBL_MAX; int bi = 0x7fffffff;
        for (int c = 0; c < 16; ++c) {
            double v = fbv[qi * 16 + c]; int i = fbi[qi * 16 + c];
            if (v < bv || (v == bv && i < bi)) { bv = v; bi = i; }
        }
        out[queueF[qi]] = (float)bi;
    }
}

// ---------------- gather quantized rows, coalesced along t ------------------
__global__ __launch_bounds__(256) void gather_kernel(const float* __restrict__ embf,
                                                     float* __restrict__ out) {
    __shared__ int cs[64];
    const int tid = threadIdx.x;
    const int m0 = blockIdx.x * 64;
    const int b = m0 >> 10;
    const int t0 = m0 & (Tt - 1);
    if (tid < 64) cs[tid] = (int)out[m0 + tid];
    __syncthreads();
    const int tq = tid & 63;
    const int dg = tid >> 6;
    const int c = cs[tq];
    const float* row = embf + (size_t)c * Dd;   // embf == exact fp32 es/clip(u)
    float* ob = out + Nq + (size_t)b * Dd * Tt + t0 + tq;
#pragma unroll 4
    for (int d = dg * 128; d < dg * 128 + 128; ++d)
        ob[(size_t)d * Tt] = row[d];
}

extern "C" void kernel_launch(void* const* d_in, const int* in_sizes, int n_in,
                              void* d_out, int out_size, void* d_ws, size_t ws_size,
                              hipStream_t stream) {
    const float* x     = (const float*)d_in[0];
    const float* es    = (const float*)d_in[1];
    const float* usage = (const float*)d_in[2];
    float* out = (float*)d_out;

    char* w = (char*)d_ws;
    ushort* Xh = (ushort*)w;   w += (size_t)Nq * Dd * 2;      // 16 MB
    ushort* Eh = (ushort*)w;   w += (size_t)Kk * Dd * 2;      //  8 MB
    ushort* Em = (ushort*)w;   w += (size_t)Kk * Dd * 2;      //  8 MB
    float*  embf = (float*)w;  w += (size_t)Kk * Dd * 4;      // 16 MB
    double* e2d = (double*)w;  w += (size_t)Kk * 8;
    float*  e2f = (float*)w;   w += (size_t)Kk * 4;
    uint4* colres = (uint4*)w; w += (size_t)Nq * 64 * 16;     // ~16.8 MB
    int* cnt = (int*)w;        w += 256;
    int* queueC = (int*)w;     w += (size_t)Nq * 4 * 4;
    int* queueF = (int*)w;     w += (size_t)Nq * 4;
    // fbv/fbi alias Xh (dead after gemm_kernel; fscan runs strictly later)
    double* fbv = (double*)Xh;
    int*    fbi = (int*)((char*)Xh + 4 * 1024 * 1024);

    init_kernel<<<1, 64, 0, stream>>>(cnt);
    split_x_kernel<<<2048, 256, 0, stream>>>(x, Xh);
    split_e_kernel<<<Kk / 4, 256, 0, stream>>>(es, usage, Eh, Em, embf, e2d, e2f);
    gemm_kernel<<<8192, 256, 0, stream>>>(Xh, Eh, Em, e2f, colres);
    merge_kernel<<<Nq / 4, 256, 0, stream>>>(colres, out, cnt, queueC, queueF);
    cand_kernel<<<128, 256, 0, stream>>>(x, embf, e2d, cnt, queueC, out);
    fscan_kernel<<<256, 256, 0, stream>>>(x, embf, e2d, cnt, queueF, fbv, fbi);
    fmerge_kernel<<<64, 256, 0, stream>>>(cnt, queueF, fbv, fbi, out);
    gather_kernel<<<Nq / 64, 256, 0, stream>>>(embf, out);
}

// Round 6
// 497.650 us; speedup vs baseline: 8.5081x; 1.0800x over previous
//
#include <hip/hip_runtime.h>
#include <hip/hip_bf16.h>
#include <cfloat>
#include <stdint.h>

#define EPS 1e-5f
constexpr int Dd = 512, Tt = 1024, Kk = 8192;
constexpr int Nq = 16 * 1024;
constexpr float TAU = 1.25f;  // >=6 sigma of 1-product bf16 error + key quant

typedef __bf16 bf16x8 __attribute__((ext_vector_type(8)));
typedef float  f32x4  __attribute__((ext_vector_type(4)));
typedef unsigned long long u64;

union Pack8 { __bf16 h[8]; int4 v; };

__device__ __forceinline__ void gld16(const void* g, void* l) {
    __builtin_amdgcn_global_load_lds(
        (const __attribute__((address_space(1))) uint32_t*)g,
        (__attribute__((address_space(3))) uint32_t*)l, 16, 0, 0);
}

// ---- monotone fp32 -> u32 key helpers --------------------------------------
__device__ __forceinline__ unsigned monokey(float s) {
    unsigned b = __float_as_uint(s);
    return b ^ ((unsigned)((int)b >> 31) | 0x80000000u);
}
__device__ __forceinline__ float unmono(unsigned u) {
    u = (u & 0x80000000u) ? (u ^ 0x80000000u) : ~u;
    return __uint_as_float(u);
}

// ---- sorted-triple merges --------------------------------------------------
__device__ __forceinline__ void merge3u(unsigned& a1, unsigned& a2, unsigned& a3,
                                        unsigned b1, unsigned b2, unsigned b3) {
    unsigned c1 = min(a1, b1);
    unsigned t  = max(a1, b1);
    unsigned u  = min(a2, b2);
    unsigned c2 = min(t, u);
    unsigned c3 = min(max(t, u), min(a3, b3));
    a1 = c1; a2 = c2; a3 = c3;
}
__device__ __forceinline__ u64 umin64(u64 a, u64 b) { return a < b ? a : b; }
__device__ __forceinline__ u64 umax64(u64 a, u64 b) { return a > b ? a : b; }
__device__ __forceinline__ void merge3q(u64& a1, u64& a2, u64& a3, u64 b1, u64 b2, u64 b3) {
    u64 c1 = umin64(a1, b1);
    u64 t  = umax64(a1, b1);
    u64 u  = umin64(a2, b2);
    u64 c2 = umin64(t, u);
    u64 c3 = umin64(umax64(t, u), umin64(a3, b3));
    a1 = c1; a2 = c2; a3 = c3;
}
__device__ __forceinline__ u64 shflx64(u64 v, int m) {
    int lo = __shfl_xor((int)(unsigned)v, m, 64);
    int hi = __shfl_xor((int)(v >> 32), m, 64);
    return ((u64)(unsigned)hi << 32) | (unsigned)lo;
}

// ---------------- init: zero queue counters ---------------------------------
__global__ void init_kernel(int* cnt) {
    if (threadIdx.x == 0 && blockIdx.x == 0) { cnt[0] = 0; cnt[1] = 0; }
}

// ---------------- P1: x (B,D,T) -> Xh (B*T, D) bf16 -------------------------
__global__ __launch_bounds__(256) void split_x_kernel(const float* __restrict__ x,
                                                      ushort* __restrict__ Xh) {
    __shared__ float Ls[64][68];
    const int tid = threadIdx.x, bid = blockIdx.x;
    const int b  = bid >> 7;
    const int d0 = ((bid >> 4) & 7) * 64;
    const int t0 = (bid & 15) * 64;
    const float* xb = x + ((size_t)b * Dd + d0) * Tt + t0;
#pragma unroll
    for (int it = 0; it < 4; ++it) {
        int s = it * 256 + tid;
        int d = s >> 4, c = (s & 15) * 4;
        float4 g = *(const float4*)(xb + (size_t)d * Tt + c);
        *(float4*)&Ls[d][c] = g;
    }
    __syncthreads();
    const int t = tid >> 2;
    const int dseg = (tid & 3) * 16;
    Pack8 ph[2];
#pragma unroll
    for (int dd = 0; dd < 16; ++dd) {
        float v = Ls[dseg + dd][t];
        ph[dd >> 3].h[dd & 7] = (__bf16)v;
    }
    size_t base = ((size_t)(b * Tt + t0 + t)) * Dd + d0 + dseg;
    *(int4*)(Xh + base)     = ph[0].v;
    *(int4*)(Xh + base + 8) = ph[1].v;
}

// ---------------- P2: emb=es/clip(u) -> Eh bf16 + embf fp32 + e2 ------------
__global__ __launch_bounds__(256) void split_e_kernel(const float* __restrict__ es,
                                                      const float* __restrict__ usage,
                                                      ushort* __restrict__ Eh,
                                                      float* __restrict__ embf,
                                                      double* __restrict__ e2d,
                                                      float* __restrict__ e2f) {
    const int wave = threadIdx.x >> 6, lane = threadIdx.x & 63;
    const int k = blockIdx.x * 4 + wave;
    const float uc = fmaxf(usage[k], EPS);
    const float* row = es + (size_t)k * Dd;
    const int d = lane * 8;
    float4 a = *(const float4*)(row + d);
    float4 c = *(const float4*)(row + d + 4);
    float ef[8] = {a.x/uc, a.y/uc, a.z/uc, a.w/uc, c.x/uc, c.y/uc, c.z/uc, c.w/uc};
    Pack8 ph;
    double e2 = 0.0;
#pragma unroll
    for (int j = 0; j < 8; ++j) {
        ph.h[j] = (__bf16)ef[j];
        e2 = fma((double)ef[j], (double)ef[j], e2);
    }
    size_t base = (size_t)k * Dd + d;
    *(int4*)(Eh + base) = ph.v;
    *(float4*)(embf + base)     = make_float4(ef[0], ef[1], ef[2], ef[3]);
    *(float4*)(embf + base + 4) = make_float4(ef[4], ef[5], ef[6], ef[7]);
#pragma unroll
    for (int off = 32; off >= 1; off >>= 1) e2 += __shfl_down(e2, off, 64);
    if (lane == 0) { e2d[k] = e2; e2f[k] = (float)e2; }
}

// ---------------- main GEMM: 128x128, 1-product bf16, top-3 epilogue --------
__global__ __launch_bounds__(256) void gemm_kernel(const ushort* __restrict__ Xh,
                                                   const ushort* __restrict__ Eh,
                                                   const float* __restrict__ e2f,
                                                   uint4* __restrict__ colres) {
    __shared__ ushort Ahs[128 * 32], Bhs[128 * 32];
    __shared__ unsigned trip[2][128][3];

    const int tid = threadIdx.x;
    const int nb = blockIdx.x & 63, mb = blockIdx.x >> 6;
    const int m0 = mb * 128, n0 = nb * 128;
    const int wave = tid >> 6, lane = tid & 63;
    const int mw = (wave >> 1) * 64, nw = (wave & 1) * 64;
    const int fm = lane & 15, fq = lane >> 4;
    const int cphys = (fq ^ ((fm >> 1) & 3)) * 8;   // read-side XOR swizzle

    f32x4 acc[4][4] = {};

    for (int d0 = 0; d0 < Dd; d0 += 32) {
#pragma unroll
        for (int j = 0; j < 2; ++j) {
            int s = j * 256 + tid;
            int r = s >> 2;
            int c = ((s & 3) ^ ((s >> 3) & 3)) * 8;  // store-side swizzle
            size_t ga = (size_t)(m0 + r) * Dd + d0 + c;
            size_t gb = (size_t)(n0 + r) * Dd + d0 + c;
            gld16(Xh + ga, (char*)Ahs + s * 16);
            gld16(Eh + gb, (char*)Bhs + s * 16);
        }
        __syncthreads();
        bf16x8 ah[4], bh[4];
#pragma unroll
        for (int i = 0; i < 4; ++i) {
            int ra = (mw + i * 16 + fm) * 32 + cphys;
            int rb = (nw + i * 16 + fm) * 32 + cphys;
            ah[i] = *(const bf16x8*)&Ahs[ra];
            bh[i] = *(const bf16x8*)&Bhs[rb];
        }
#pragma unroll
        for (int i = 0; i < 4; ++i)
#pragma unroll
            for (int j = 0; j < 4; ++j)
                acc[i][j] = __builtin_amdgcn_mfma_f32_16x16x32_bf16(ah[i], bh[j], acc[i][j], 0, 0, 0);
        __syncthreads();
    }

    float e2r[4];
#pragma unroll
    for (int j = 0; j < 4; ++j) e2r[j] = e2f[n0 + nw + j * 16 + fm];

    // top-3 per (row, 128-col block); u32 keys, low 7 bits = col-in-block
#pragma unroll
    for (int i = 0; i < 4; ++i)
#pragma unroll
        for (int r = 0; r < 4; ++r) {
            unsigned k[4];
#pragma unroll
            for (int j = 0; j < 4; ++j) {
                float s = fmaf(-2.0f, acc[i][j][r], e2r[j]);
                k[j] = (monokey(s) & 0xFFFFFF80u) | (unsigned)(nw + j * 16 + fm);
            }
            unsigned lo01 = min(k[0], k[1]), hi01 = max(k[0], k[1]);
            unsigned lo23 = min(k[2], k[3]), hi23 = max(k[2], k[3]);
            unsigned a1 = min(lo01, lo23);
            unsigned t  = max(lo01, lo23), u = min(hi01, hi23);
            unsigned a2 = min(t, u);
            unsigned a3 = max(t, u);        // 3rd smallest of the 4
#pragma unroll
            for (int st = 1; st < 16; st <<= 1) {
                unsigned b1 = __shfl_xor(a1, st, 64);
                unsigned b2 = __shfl_xor(a2, st, 64);
                unsigned b3 = __shfl_xor(a3, st, 64);
                merge3u(a1, a2, a3, b1, b2, b3);
            }
            if (fm == 0) {
                int rl = mw + i * 16 + fq * 4 + r;
                trip[wave & 1][rl][0] = a1;
                trip[wave & 1][rl][1] = a2;
                trip[wave & 1][rl][2] = a3;
            }
        }
    __syncthreads();
    if (tid < 128) {
        unsigned a1 = trip[0][tid][0], a2 = trip[0][tid][1], a3 = trip[0][tid][2];
        merge3u(a1, a2, a3, trip[1][tid][0], trip[1][tid][1], trip[1][tid][2]);
        colres[(size_t)(m0 + tid) * 64 + nb] = make_uint4(a1, a2, a3, 0u);
    }
}

// ---------------- merge 64 col-blocks -> global top-3; tiered flagging ------
__global__ __launch_bounds__(256) void merge_kernel(const uint4* __restrict__ colres,
                                                    float* __restrict__ out,
                                                    int* __restrict__ cnt,
                                                    int* __restrict__ queueC,
                                                    int* __restrict__ queueF) {
    const int wave = threadIdx.x >> 6, lane = threadIdx.x & 63;
    const int row = blockIdx.x * 4 + wave;
    uint4 q = colres[(size_t)row * 64 + lane];
    const unsigned nb128 = (unsigned)(lane * 128);
    u64 a1 = ((u64)(q.x & 0xFFFFFF80u) << 32) | (nb128 + (q.x & 127u));
    u64 a2 = ((u64)(q.y & 0xFFFFFF80u) << 32) | (nb128 + (q.y & 127u));
    u64 a3 = ((u64)(q.z & 0xFFFFFF80u) << 32) | (nb128 + (q.z & 127u));
#pragma unroll
    for (int st = 1; st < 64; st <<= 1)
        merge3q(a1, a2, a3, shflx64(a1, st), shflx64(a2, st), shflx64(a3, st));
    if (lane == 0) {
        float v1 = unmono((unsigned)(a1 >> 32));
        float v2 = unmono((unsigned)(a2 >> 32));
        float v3 = unmono((unsigned)(a3 >> 32));
        int i1 = (int)(unsigned)a1, i2 = (int)(unsigned)a2;
        out[row] = (float)i1;
        if (v3 - v1 < TAU) {                    // winner may be outside top-3
            int p = atomicAdd(&cnt[1], 1);
            queueF[p] = row;
        } else if (v2 - v1 < TAU) {             // winner provably in {i1,i2}
            int p = atomicAdd(&cnt[0], 1);
            queueC[p * 4] = row; queueC[p * 4 + 1] = i1; queueC[p * 4 + 2] = i2;
        }
    }
}

// ---------------- pair rescore: exact fp64 on {i1,i2}, one wave per query ---
__global__ __launch_bounds__(256) void cand_kernel(const float* __restrict__ x,
                                                   const float* __restrict__ embf,
                                                   const double* __restrict__ e2d,
                                                   const int* __restrict__ cnt,
                                                   const int* __restrict__ queueC,
                                                   float* __restrict__ out) {
    const int wv = (blockIdx.x << 2) | (threadIdx.x >> 6);
    const int lane = threadIdx.x & 63;
    const int n = cnt[0];
    for (int p = wv; p < n; p += gridDim.x * 4) {
        int row = queueC[p * 4], i1 = queueC[p * 4 + 1], i2 = queueC[p * 4 + 2];
        int b = row >> 10, t = row & 1023;
        const float* xb = x + (size_t)b * Dd * Tt + t;
        const int d0 = lane * 8;
        const float* e0 = embf + (size_t)i1 * Dd + d0;
        const float* e1 = embf + (size_t)i2 * Dd + d0;
        double s0 = 0.0, s1 = 0.0;
#pragma unroll
        for (int j = 0; j < 8; ++j) {
            double xv = (double)xb[(size_t)(d0 + j) * Tt];
            s0 = fma(xv, (double)e0[j], s0);
            s1 = fma(xv, (double)e1[j], s1);
        }
#pragma unroll
        for (int off = 32; off >= 1; off >>= 1) {
            s0 += __shfl_down(s0, off, 64);
            s1 += __shfl_down(s1, off, 64);
        }
        if (lane == 0) {
            double d1 = fma(-2.0, s0, e2d[i1]);
            double d2 = fma(-2.0, s1, e2d[i2]);
            int c = (d2 < d1 || (d2 == d1 && i2 < i1)) ? i2 : i1;
            out[row] = (float)c;
        }
    }
}

// ---------------- rare full exact scan: 16 chunks x 512 clusters per query --
__global__ __launch_bounds__(256) void fscan_kernel(const float* __restrict__ x,
                                                    const float* __restrict__ embf,
                                                    const double* __restrict__ e2d,
                                                    const int* __restrict__ cnt,
                                                    const int* __restrict__ queueF,
                                                    double* __restrict__ fbv,
                                                    int* __restrict__ fbi) {
    __shared__ float xs[512];
    __shared__ double sv[256];
    __shared__ int si[256];
    const int tid = threadIdx.x;
    const int ntask = cnt[1] * 16;
    for (int task = blockIdx.x; task < ntask; task += gridDim.x) {
        int qi = task >> 4, ch = task & 15;
        int row = queueF[qi];
        int b = row >> 10, t = row & 1023;
        __syncthreads();
        for (int d = tid; d < Dd; d += 256)
            xs[d] = x[((size_t)b * Dd + d) * Tt + t];
        __syncthreads();
        double bv = DBL_MAX; int bi = 0x7fffffff;
#pragma unroll
        for (int c = 0; c < 2; ++c) {
            int k = ch * 512 + c * 256 + tid;
            const float* er = embf + (size_t)k * Dd;
            double a0 = 0, a1 = 0, a2 = 0, a3 = 0;
            for (int d = 0; d < Dd; d += 4) {
                float4 e = *(const float4*)(er + d);
                float4 xv = *(const float4*)&xs[d];
                a0 = fma((double)e.x, (double)xv.x, a0);
                a1 = fma((double)e.y, (double)xv.y, a1);
                a2 = fma((double)e.z, (double)xv.z, a2);
                a3 = fma((double)e.w, (double)xv.w, a3);
            }
            double s = fma(-2.0, (a0 + a1) + (a2 + a3), e2d[k]);
            if (s < bv || (s == bv && k < bi)) { bv = s; bi = k; }
        }
        sv[tid] = bv; si[tid] = bi;
        __syncthreads();
        for (int off = 128; off > 0; off >>= 1) {
            if (tid < off) {
                if (sv[tid + off] < sv[tid] ||
                    (sv[tid + off] == sv[tid] && si[tid + off] < si[tid])) {
                    sv[tid] = sv[tid + off]; si[tid] = si[tid + off];
                }
            }
            __syncthreads();
        }
        if (tid == 0) { fbv[task] = sv[0]; fbi[task] = si[0]; }
    }
}

__global__ void fmerge_kernel(const int* __restrict__ cnt,
                              const int* __restrict__ queueF,
                              const double* __restrict__ fbv,
                              const int* __restrict__ fbi,
                              float* __restrict__ out) {
    const int nF = cnt[1];
    for (int qi = blockIdx.x * 256 + threadIdx.x; qi < nF; qi += gridDim.x * 256) {
        double bv = DBL_MAX; int bi = 0x7fffffff;
        for (int c = 0; c < 16; ++c) {
            double v = fbv[qi * 16 + c]; int i = fbi[qi * 16 + c];
            if (v < bv || (v == bv && i < bi)) { bv = v; bi = i; }
        }
        out[queueF[qi]] = (float)bi;
    }
}

// ---------------- gather quantized rows, coalesced along t ------------------
__global__ __launch_bounds__(256) void gather_kernel(const float* __restrict__ embf,
                                                     float* __restrict__ out) {
    __shared__ int cs[64];
    const int tid = threadIdx.x;
    const int m0 = blockIdx.x * 64;
    const int b = m0 >> 10;
    const int t0 = m0 & (Tt - 1);
    if (tid < 64) cs[tid] = (int)out[m0 + tid];
    __syncthreads();
    const int tq = tid & 63;
    const int dg = tid >> 6;
    const int c = cs[tq];
    const float* row = embf + (size_t)c * Dd;   // embf == exact fp32 es/clip(u)
    float* ob = out + Nq + (size_t)b * Dd * Tt + t0 + tq;
#pragma unroll 4
    for (int d = dg * 128; d < dg * 128 + 128; ++d)
        ob[(size_t)d * Tt] = row[d];
}

extern "C" void kernel_launch(void* const* d_in, const int* in_sizes, int n_in,
                              void* d_out, int out_size, void* d_ws, size_t ws_size,
                              hipStream_t stream) {
    const float* x     = (const float*)d_in[0];
    const float* es    = (const float*)d_in[1];
    const float* usage = (const float*)d_in[2];
    float* out = (float*)d_out;

    char* w = (char*)d_ws;
    ushort* Xh = (ushort*)w;   w += (size_t)Nq * Dd * 2;      // 16 MB
    ushort* Eh = (ushort*)w;   w += (size_t)Kk * Dd * 2;      //  8 MB
    float*  embf = (float*)w;  w += (size_t)Kk * Dd * 4;      // 16 MB
    double* e2d = (double*)w;  w += (size_t)Kk * 8;
    float*  e2f = (float*)w;   w += (size_t)Kk * 4;
    uint4* colres = (uint4*)w; w += (size_t)Nq * 64 * 16;     // ~16.8 MB
    int* cnt = (int*)w;        w += 256;
    int* queueC = (int*)w;     w += (size_t)Nq * 4 * 4;
    int* queueF = (int*)w;     w += (size_t)Nq * 4;
    // fbv/fbi alias Xh (dead after gemm_kernel; fscan runs strictly later)
    double* fbv = (double*)Xh;
    int*    fbi = (int*)((char*)Xh + 4 * 1024 * 1024);

    init_kernel<<<1, 64, 0, stream>>>(cnt);
    split_x_kernel<<<2048, 256, 0, stream>>>(x, Xh);
    split_e_kernel<<<Kk / 4, 256, 0, stream>>>(es, usage, Eh, embf, e2d, e2f);
    gemm_kernel<<<8192, 256, 0, stream>>>(Xh, Eh, e2f, colres);
    merge_kernel<<<Nq / 4, 256, 0, stream>>>(colres, out, cnt, queueC, queueF);
    cand_kernel<<<128, 256, 0, stream>>>(x, embf, e2d, cnt, queueC, out);
    fscan_kernel<<<256, 256, 0, stream>>>(x, embf, e2d, cnt, queueF, fbv, fbi);
    fmerge_kernel<<<64, 256, 0, stream>>>(cnt, queueF, fbv, fbi, out);
    gather_kernel<<<Nq / 64, 256, 0, stream>>>(embf, out);
}

// Round 7
// 423.268 us; speedup vs baseline: 10.0032x; 1.1757x over previous
//
#include <hip/hip_runtime.h>
#include <hip/hip_bf16.h>
#include <cfloat>
#include <stdint.h>

#define EPS 1e-5f
constexpr int Dd = 512, Tt = 1024, Kk = 8192;
constexpr int Nq = 16 * 1024;
constexpr float TAU = 1.5f;   // ~7 sigma of 1-product bf16 error + key quant

typedef __bf16 bf16x8 __attribute__((ext_vector_type(8)));
typedef float  f32x4  __attribute__((ext_vector_type(4)));
typedef unsigned long long u64;

union Pack8 { __bf16 h[8]; int4 v; };

__device__ __forceinline__ void gld16(const void* g, void* l) {
    __builtin_amdgcn_global_load_lds(
        (const __attribute__((address_space(1))) uint32_t*)g,
        (__attribute__((address_space(3))) uint32_t*)l, 16, 0, 0);
}

// ---- monotone fp32 -> u32 key helpers --------------------------------------
__device__ __forceinline__ unsigned monokey(float s) {
    unsigned b = __float_as_uint(s);
    return b ^ ((unsigned)((int)b >> 31) | 0x80000000u);
}
__device__ __forceinline__ float unmono(unsigned u) {
    u = (u & 0x80000000u) ? (u ^ 0x80000000u) : ~u;
    return __uint_as_float(u);
}

// ---- sorted-pair / sorted-quad merges --------------------------------------
__device__ __forceinline__ void merge2u(unsigned& a1, unsigned& a2, unsigned b1, unsigned b2) {
    unsigned c1 = min(a1, b1);
    unsigned c2 = min(max(a1, b1), min(a2, b2));
    a1 = c1; a2 = c2;
}
__device__ __forceinline__ u64 umin64(u64 a, u64 b) { return a < b ? a : b; }
__device__ __forceinline__ u64 umax64(u64 a, u64 b) { return a > b ? a : b; }
__device__ __forceinline__ void merge4q(u64& a1, u64& a2, u64& a3, u64& a4,
                                        u64 b1, u64 b2, u64 b3, u64 b4) {
    u64 c1 = umin64(a1, b1);
    u64 c2 = umin64(umin64(a2, b2), umax64(a1, b1));
    u64 c3 = umin64(umin64(a3, b3), umin64(umax64(a2, b1), umax64(a1, b2)));
    u64 c4 = umin64(umin64(a4, b4), umin64(umax64(a3, b1), umax64(a1, b3)));
    c4 = umin64(c4, umax64(a2, b2));
    a1 = c1; a2 = c2; a3 = c3; a4 = c4;
}
__device__ __forceinline__ u64 shflx64(u64 v, int m) {
    int lo = __shfl_xor((int)(unsigned)v, m, 64);
    int hi = __shfl_xor((int)(v >> 32), m, 64);
    return ((u64)(unsigned)hi << 32) | (unsigned)lo;
}

// ---------------- P1: x (B,D,T) -> Xh bf16 + Xf fp32, both (B*T, D) ---------
__global__ __launch_bounds__(256) void split_x_kernel(const float* __restrict__ x,
                                                      ushort* __restrict__ Xh,
                                                      float* __restrict__ Xf,
                                                      int* __restrict__ cnt) {
    if (blockIdx.x == 0 && threadIdx.x < 2) cnt[threadIdx.x] = 0;
    __shared__ float Ls[64][68];
    const int tid = threadIdx.x, bid = blockIdx.x;
    const int b  = bid >> 7;
    const int d0 = ((bid >> 4) & 7) * 64;
    const int t0 = (bid & 15) * 64;
    const float* xb = x + ((size_t)b * Dd + d0) * Tt + t0;
#pragma unroll
    for (int it = 0; it < 4; ++it) {
        int s = it * 256 + tid;
        int d = s >> 4, c = (s & 15) * 4;
        float4 g = *(const float4*)(xb + (size_t)d * Tt + c);
        *(float4*)&Ls[d][c] = g;
    }
    __syncthreads();
    const int t = tid >> 2;
    const int dseg = (tid & 3) * 16;
    Pack8 ph[2];
    float vf[16];
#pragma unroll
    for (int dd = 0; dd < 16; ++dd) {
        float v = Ls[dseg + dd][t];
        vf[dd] = v;
        ph[dd >> 3].h[dd & 7] = (__bf16)v;
    }
    size_t base = ((size_t)(b * Tt + t0 + t)) * Dd + d0 + dseg;
    *(int4*)(Xh + base)     = ph[0].v;
    *(int4*)(Xh + base + 8) = ph[1].v;
#pragma unroll
    for (int g = 0; g < 4; ++g)
        *(float4*)(Xf + base + g * 4) = make_float4(vf[g*4], vf[g*4+1], vf[g*4+2], vf[g*4+3]);
}

// ---------------- P2: emb=es/clip(u) -> Eh bf16 + embf fp32 + e2 ------------
__global__ __launch_bounds__(256) void split_e_kernel(const float* __restrict__ es,
                                                      const float* __restrict__ usage,
                                                      ushort* __restrict__ Eh,
                                                      float* __restrict__ embf,
                                                      double* __restrict__ e2d,
                                                      float* __restrict__ e2f) {
    const int wave = threadIdx.x >> 6, lane = threadIdx.x & 63;
    const int k = blockIdx.x * 4 + wave;
    const float uc = fmaxf(usage[k], EPS);
    const float* row = es + (size_t)k * Dd;
    const int d = lane * 8;
    float4 a = *(const float4*)(row + d);
    float4 c = *(const float4*)(row + d + 4);
    float ef[8] = {a.x/uc, a.y/uc, a.z/uc, a.w/uc, c.x/uc, c.y/uc, c.z/uc, c.w/uc};
    Pack8 ph;
    double e2 = 0.0;
#pragma unroll
    for (int j = 0; j < 8; ++j) {
        ph.h[j] = (__bf16)ef[j];
        e2 = fma((double)ef[j], (double)ef[j], e2);
    }
    size_t base = (size_t)k * Dd + d;
    *(int4*)(Eh + base) = ph.v;
    *(float4*)(embf + base)     = make_float4(ef[0], ef[1], ef[2], ef[3]);
    *(float4*)(embf + base + 4) = make_float4(ef[4], ef[5], ef[6], ef[7]);
#pragma unroll
    for (int off = 32; off >= 1; off >>= 1) e2 += __shfl_down(e2, off, 64);
    if (lane == 0) { e2d[k] = e2; e2f[k] = (float)e2; }
}

// ---------------- main GEMM: 128x128, 1-product bf16, top-2 epilogue --------
__global__ __launch_bounds__(256) void gemm_kernel(const ushort* __restrict__ Xh,
                                                   const ushort* __restrict__ Eh,
                                                   const float* __restrict__ e2f,
                                                   uint2* __restrict__ colres) {
    __shared__ ushort Ahs[128 * 32], Bhs[128 * 32];
    __shared__ unsigned trip[2][128][2];

    const int tid = threadIdx.x;
    const int nb = blockIdx.x & 63, mb = blockIdx.x >> 6;
    const int m0 = mb * 128, n0 = nb * 128;
    const int wave = tid >> 6, lane = tid & 63;
    const int mw = (wave >> 1) * 64, nw = (wave & 1) * 64;
    const int fm = lane & 15, fq = lane >> 4;
    const int cphys = (fq ^ ((fm >> 1) & 3)) * 8;   // read-side XOR swizzle

    f32x4 acc[4][4] = {};

    for (int d0 = 0; d0 < Dd; d0 += 32) {
#pragma unroll
        for (int j = 0; j < 2; ++j) {
            int s = j * 256 + tid;
            int r = s >> 2;
            int c = ((s & 3) ^ ((s >> 3) & 3)) * 8;  // store-side swizzle
            size_t ga = (size_t)(m0 + r) * Dd + d0 + c;
            size_t gb = (size_t)(n0 + r) * Dd + d0 + c;
            gld16(Xh + ga, (char*)Ahs + s * 16);
            gld16(Eh + gb, (char*)Bhs + s * 16);
        }
        __syncthreads();
        bf16x8 ah[4], bh[4];
#pragma unroll
        for (int i = 0; i < 4; ++i) {
            int ra = (mw + i * 16 + fm) * 32 + cphys;
            int rb = (nw + i * 16 + fm) * 32 + cphys;
            ah[i] = *(const bf16x8*)&Ahs[ra];
            bh[i] = *(const bf16x8*)&Bhs[rb];
        }
#pragma unroll
        for (int i = 0; i < 4; ++i)
#pragma unroll
            for (int j = 0; j < 4; ++j)
                acc[i][j] = __builtin_amdgcn_mfma_f32_16x16x32_bf16(ah[i], bh[j], acc[i][j], 0, 0, 0);
        __syncthreads();
    }

    float e2r[4];
#pragma unroll
    for (int j = 0; j < 4; ++j) e2r[j] = e2f[n0 + nw + j * 16 + fm];

    // top-2 per (row, 128-col block); u32 keys, low 7 bits = col-in-block
#pragma unroll
    for (int i = 0; i < 4; ++i)
#pragma unroll
        for (int r = 0; r < 4; ++r) {
            unsigned k[4];
#pragma unroll
            for (int j = 0; j < 4; ++j) {
                float s = fmaf(-2.0f, acc[i][j][r], e2r[j]);
                k[j] = (monokey(s) & 0xFFFFFF80u) | (unsigned)(nw + j * 16 + fm);
            }
            unsigned lo01 = min(k[0], k[1]), hi01 = max(k[0], k[1]);
            unsigned lo23 = min(k[2], k[3]), hi23 = max(k[2], k[3]);
            unsigned a1 = min(lo01, lo23);
            unsigned a2 = min(max(lo01, lo23), min(hi01, hi23));
#pragma unroll
            for (int st = 1; st < 16; st <<= 1) {
                unsigned b1 = __shfl_xor(a1, st, 64);
                unsigned b2 = __shfl_xor(a2, st, 64);
                merge2u(a1, a2, b1, b2);
            }
            if (fm == 0) {
                int rl = mw + i * 16 + fq * 4 + r;
                trip[wave & 1][rl][0] = a1;
                trip[wave & 1][rl][1] = a2;
            }
        }
    __syncthreads();
    if (tid < 128) {
        unsigned a1 = trip[0][tid][0], a2 = trip[0][tid][1];
        merge2u(a1, a2, trip[1][tid][0], trip[1][tid][1]);
        colres[(size_t)(m0 + tid) * 64 + nb] = make_uint2(a1, a2);
    }
}

// ------- merge: global top-4 of block-pairs + collision ballot; tiering -----
__global__ __launch_bounds__(256) void merge_kernel(const uint2* __restrict__ colres,
                                                    float* __restrict__ out,
                                                    int* __restrict__ cnt,
                                                    int* __restrict__ queueC,
                                                    int* __restrict__ queueF) {
    const int wave = threadIdx.x >> 6, lane = threadIdx.x & 63;
    const int row = blockIdx.x * 4 + wave;
    uint2 q = colres[(size_t)row * 64 + lane];
    const unsigned nb128 = (unsigned)(lane * 128);
    u64 a1 = ((u64)(q.x & 0xFFFFFF80u) << 32) | (nb128 + (q.x & 127u));
    u64 a2 = ((u64)(q.y & 0xFFFFFF80u) << 32) | (nb128 + (q.y & 127u));
    u64 a3 = ~0ull, a4 = ~0ull;
#pragma unroll
    for (int st = 1; st < 64; st <<= 1)
        merge4q(a1, a2, a3, a4, shflx64(a1, st), shflx64(a2, st), shflx64(a3, st), shflx64(a4, st));
    // all lanes hold the global top-4 now
    float v1 = unmono((unsigned)(a1 >> 32));
    // block-collision: this lane's block has 2+ entries within TAU of global min
    u64 coll = __ballot(unmono(q.y) < v1 + TAU);
    if (lane == 0) {
        float v2 = unmono((unsigned)(a2 >> 32));
        float v4 = unmono((unsigned)(a4 >> 32));
        int i1 = (int)(unsigned)a1;
        out[row] = (float)i1;
        if (coll != 0ull || (v4 - v1 < TAU)) {   // candidate set may be incomplete
            int p = atomicAdd(&cnt[1], 1);
            queueF[p] = row;
        } else if (v2 - v1 < TAU) {              // winner provably in {i1..i4}
            int p = atomicAdd(&cnt[0], 1);
            queueC[p * 5]     = row;
            queueC[p * 5 + 1] = i1;
            queueC[p * 5 + 2] = (int)(unsigned)a2;
            queueC[p * 5 + 3] = (int)(unsigned)a3;
            queueC[p * 5 + 4] = (int)(unsigned)a4;
        }
    }
}

// ------- candidate rescore: exact fp64 on {i1..i4}, one wave per query ------
__global__ __launch_bounds__(256) void cand_kernel(const float* __restrict__ Xf,
                                                   const float* __restrict__ embf,
                                                   const double* __restrict__ e2d,
                                                   const int* __restrict__ cnt,
                                                   const int* __restrict__ queueC,
                                                   float* __restrict__ out) {
    const int wv = (blockIdx.x << 2) | (threadIdx.x >> 6);
    const int lane = threadIdx.x & 63;
    const int n = cnt[0];
    for (int p = wv; p < n; p += gridDim.x * 4) {
        int row = queueC[p * 5];
        int ci[4] = {queueC[p*5+1], queueC[p*5+2], queueC[p*5+3], queueC[p*5+4]};
        const float* xr = Xf + (size_t)row * Dd + lane * 8;
        float4 xa = *(const float4*)xr;
        float4 xb = *(const float4*)(xr + 4);
        double s[4] = {0.0, 0.0, 0.0, 0.0};
#pragma unroll
        for (int c = 0; c < 4; ++c) {
            const float* er = embf + (size_t)ci[c] * Dd + lane * 8;
            float4 ea = *(const float4*)er;
            float4 eb = *(const float4*)(er + 4);
            double t = 0.0;
            t = fma((double)xa.x, (double)ea.x, t);
            t = fma((double)xa.y, (double)ea.y, t);
            t = fma((double)xa.z, (double)ea.z, t);
            t = fma((double)xa.w, (double)ea.w, t);
            t = fma((double)xb.x, (double)eb.x, t);
            t = fma((double)xb.y, (double)eb.y, t);
            t = fma((double)xb.z, (double)eb.z, t);
            t = fma((double)xb.w, (double)eb.w, t);
            s[c] = t;
        }
#pragma unroll
        for (int off = 32; off >= 1; off >>= 1) {
#pragma unroll
            for (int c = 0; c < 4; ++c) s[c] += __shfl_down(s[c], off, 64);
        }
        if (lane == 0) {
            double bv = DBL_MAX; int bi = 0x7fffffff;
#pragma unroll
            for (int c = 0; c < 4; ++c) {
                double dv = fma(-2.0, s[c], e2d[ci[c]]);
                if (dv < bv || (dv == bv && ci[c] < bi)) { bv = dv; bi = ci[c]; }
            }
            out[row] = (float)bi;
        }
    }
}

// ---------------- rare full exact scan: 16 chunks x 512 clusters per query --
__global__ __launch_bounds__(256) void fscan_kernel(const float* __restrict__ Xf,
                                                    const float* __restrict__ embf,
                                                    const double* __restrict__ e2d,
                                                    const int* __restrict__ cnt,
                                                    const int* __restrict__ queueF,
                                                    double* __restrict__ fbv,
                                                    int* __restrict__ fbi) {
    __shared__ float xs[512];
    __shared__ double sv[256];
    __shared__ int si[256];
    const int tid = threadIdx.x;
    const int ntask = cnt[1] * 16;
    for (int task = blockIdx.x; task < ntask; task += gridDim.x) {
        int qi = task >> 4, ch = task & 15;
        int row = queueF[qi];
        __syncthreads();
        for (int d = tid; d < Dd; d += 256)
            xs[d] = Xf[(size_t)row * Dd + d];
        __syncthreads();
        double bv = DBL_MAX; int bi = 0x7fffffff;
#pragma unroll
        for (int c = 0; c < 2; ++c) {
            int k = ch * 512 + c * 256 + tid;
            const float* er = embf + (size_t)k * Dd;
            double a0 = 0, a1 = 0, a2 = 0, a3 = 0;
            for (int d = 0; d < Dd; d += 4) {
                float4 e = *(const float4*)(er + d);
                float4 xv = *(const float4*)&xs[d];
                a0 = fma((double)e.x, (double)xv.x, a0);
                a1 = fma((double)e.y, (double)xv.y, a1);
                a2 = fma((double)e.z, (double)xv.z, a2);
                a3 = fma((double)e.w, (double)xv.w, a3);
            }
            double s = fma(-2.0, (a0 + a1) + (a2 + a3), e2d[k]);
            if (s < bv || (s == bv && k < bi)) { bv = s; bi = k; }
        }
        sv[tid] = bv; si[tid] = bi;
        __syncthreads();
        for (int off = 128; off > 0; off >>= 1) {
            if (tid < off) {
                if (sv[tid + off] < sv[tid] ||
                    (sv[tid + off] == sv[tid] && si[tid + off] < si[tid])) {
                    sv[tid] = sv[tid + off]; si[tid] = si[tid + off];
                }
            }
            __syncthreads();
        }
        if (tid == 0) { fbv[task] = sv[0]; fbi[task] = si[0]; }
    }
}

__global__ void fmerge_kernel(const int* __restrict__ cnt,
                              const int* __restrict__ queueF,
                              const double* __restrict__ fbv,
                              const int* __restrict__ fbi,
                              float* __restrict__ out) {
    const int nF = cnt[1];
    for (int qi = blockIdx.x * 256 + threadIdx.x; qi < nF; qi += gridDim.x * 256) {
        double bv = DBL_MAX; int bi = 0x7fffffff;
        for (int c = 0; c < 16; ++c) {
            double v = fbv[qi * 16 + c]; int i = fbi[qi * 16 + c];
            if (v < bv || (v == bv && i < bi)) { bv = v; bi = i; }
        }
        out[queueF[qi]] = (float)bi;
    }
}

// ---------------- gather quantized rows, coalesced along t ------------------
__global__ __launch_bounds__(256) void gather_kernel(const float* __restrict__ embf,
                                                     float* __restrict__ out) {
    __shared__ int cs[64];
    const int tid = threadIdx.x;
    const int m0 = blockIdx.x * 64;
    const int b = m0 >> 10;
    const int t0 = m0 & (Tt - 1);
    if (tid < 64) cs[tid] = (int)out[m0 + tid];
    __syncthreads();
    const int tq = tid & 63;
    const int dg = tid >> 6;
    const int c = cs[tq];
    const float* row = embf + (size_t)c * Dd;   // embf == exact fp32 es/clip(u)
    float* ob = out + Nq + (size_t)b * Dd * Tt + t0 + tq;
#pragma unroll 4
    for (int d = dg * 128; d < dg * 128 + 128; ++d)
        ob[(size_t)d * Tt] = row[d];
}

extern "C" void kernel_launch(void* const* d_in, const int* in_sizes, int n_in,
                              void* d_out, int out_size, void* d_ws, size_t ws_size,
                              hipStream_t stream) {
    const float* x     = (const float*)d_in[0];
    const float* es    = (const float*)d_in[1];
    const float* usage = (const float*)d_in[2];
    float* out = (float*)d_out;

    char* w = (char*)d_ws;
    ushort* Xh = (ushort*)w;   w += (size_t)Nq * Dd * 2;      // 16 MB
    ushort* Eh = (ushort*)w;   w += (size_t)Kk * Dd * 2;      //  8 MB
    float*  Xf = (float*)w;    w += (size_t)Nq * Dd * 4;      // 32 MB
    float*  embf = (float*)w;  w += (size_t)Kk * Dd * 4;      // 16 MB
    double* e2d = (double*)w;  w += (size_t)Kk * 8;
    float*  e2f = (float*)w;   w += (size_t)Kk * 4;
    uint2* colres = (uint2*)w; w += (size_t)Nq * 64 * 8;      // 8.4 MB
    int* cnt = (int*)w;        w += 256;
    int* queueC = (int*)w;     w += (size_t)Nq * 5 * 4;
    int* queueF = (int*)w;     w += (size_t)Nq * 4;
    // fbv/fbi alias Xh (dead after gemm_kernel; fscan runs strictly later)
    double* fbv = (double*)Xh;
    int*    fbi = (int*)((char*)Xh + 4 * 1024 * 1024);

    split_x_kernel<<<2048, 256, 0, stream>>>(x, Xh, Xf, cnt);
    split_e_kernel<<<Kk / 4, 256, 0, stream>>>(es, usage, Eh, embf, e2d, e2f);
    gemm_kernel<<<8192, 256, 0, stream>>>(Xh, Eh, e2f, colres);
    merge_kernel<<<Nq / 4, 256, 0, stream>>>(colres, out, cnt, queueC, queueF);
    cand_kernel<<<256, 256, 0, stream>>>(Xf, embf, e2d, cnt, queueC, out);
    fscan_kernel<<<256, 256, 0, stream>>>(Xf, embf, e2d, cnt, queueF, fbv, fbi);
    fmerge_kernel<<<64, 256, 0, stream>>>(cnt, queueF, fbv, fbi, out);
    gather_kernel<<<Nq / 64, 256, 0, stream>>>(embf, out);
}